// Round 5
// baseline (196.337 us; speedup 1.0000x reference)
//
#include <hip/hip_runtime.h>
#include <hip/hip_fp16.h>

// Problem dims
#define BDIM 32
#define NDIM 400
#define TDIM 315
#define TPAD 320
#define DDIM 512
#define HDIM 256
#define NITER 100

// Workspace layout (bytes)
#define OFS_TAB   0u          // tAb bf16 [320][512] = 327680
#define OFS_TB    327680u     // TB f32 [320][256] = 327680
#define OFS_STATS 655360u     // stats[32][2] f32 = 256
#define OFS_WHB   655616u     // Whb bf16 [512][256] = 262144
#define OFS_S     1048576u    // s fp16 [32][400][320] = 8192000
#define OFS_S1B   9240576u    // s1b bf16 [32][400][320] = 8192000
#define OFS_F1    17432576u   // f1b bf16 [32][315][512] = 10321920  (end 27754496)
#define OFS_FB    27754496u   // Fb bf16 [32][400][512] = 13107200  (end 40861696)
// k_sinkhorn scratch overlaps the f1b region (f1b is produced AFTER sinkhorn):
// qpart: tagged pairs (u32 tag | f32 data) [2 parity][32 b][8 c][320] ull = 1310720 B
#define OFS_QPART (OFS_F1 + 4096u)

typedef __attribute__((ext_vector_type(8))) short bf16x8;
typedef __attribute__((ext_vector_type(4))) float f32x4;
typedef unsigned long long ull;

// ---------------- bf16 pack/unpack (RNE) ----------------
__device__ __forceinline__ unsigned rne_hi(float x) {
  unsigned u = __float_as_uint(x);
  u += 0x7fffu + ((u >> 16) & 1u);
  return u & 0xffff0000u;
}
__device__ __forceinline__ unsigned pack2(float lo, float hi) {
  return (rne_hi(lo) >> 16) | rne_hi(hi);
}
__device__ __forceinline__ unsigned short bf1(float x) { return (unsigned short)(rne_hi(x) >> 16); }
__device__ __forceinline__ float bfres(float x) {  // x - bf16(x), the lo part
  return x - __uint_as_float(rne_hi(x));
}

// ---------------- DPP wave reduce helpers (VALU pipe, no LDS) ----------------
template <int CTRL, int RMASK>
__device__ __forceinline__ float dppadd(float x) {
  int y = __builtin_amdgcn_update_dpp(0, __float_as_int(x), CTRL, RMASK, 0xf, true);
  return x + __int_as_float(y);
}
template <int CTRL, int RMASK>
__device__ __forceinline__ float dppmax(float x) {
  int y = __builtin_amdgcn_update_dpp(0, __float_as_int(x), CTRL, RMASK, 0xf, true);
  return fmaxf(x, __int_as_float(y));
}

#define LDH 40

// ---------------- K0: fused prep ------------------------------------------------------------
// blocks 0..39   : tA = text @ A^T  via bf16x3 split MFMA, fp32->hi/lo converted in-register
// blocks 40..59  : TB = text @ Wh_bot + bh, same split MFMA
// blocks 60..511 : grid-stride packing (Fb, Whb top) + zero-init (stats, qpart tags)
// GEMM planes read raw fp32 inputs; no hi/lo global buffers exist anymore.
__global__ __launch_bounds__(256) void k_prep(const float* __restrict__ F,
                                              const float* __restrict__ Wh,
                                              const float* __restrict__ text,
                                              const float* __restrict__ A,
                                              const float* __restrict__ bh,
                                              unsigned short* __restrict__ Fb,
                                              unsigned short* __restrict__ Whb,
                                              unsigned short* __restrict__ tAb,
                                              float* __restrict__ TB,
                                              float* __restrict__ stats,
                                              uint4* __restrict__ qzero) {
  __shared__ unsigned short Ahs[64 * LDH], Als[64 * LDH];
  __shared__ unsigned short Bhs[64 * LDH], Bls[64 * LDH];
  const int bid = blockIdx.x, tid = threadIdx.x;
  if (bid >= 60) {
    // ---- packing plane ----
    const int NF4 = (BDIM * NDIM * DDIM) / 4;      // 1638400
    const int NW4 = (DDIM * HDIM) / 4;             // 32768 (top half of Wh)
    const int NQ4 = (2 * BDIM * 8 * 320 * 2) / 4;  // 81920
    const int gid = (bid - 60) * 256 + tid;
    const int stride = 452 * 256;
    for (int i = gid; i < NF4; i += stride) {
      float4 v = ((const float4*)F)[i];
      ((uint2*)Fb)[i] = make_uint2(pack2(v.x, v.y), pack2(v.z, v.w));
    }
    for (int i = gid; i < NW4; i += stride) {
      float4 v = ((const float4*)Wh)[i];
      ((uint2*)Whb)[i] = make_uint2(pack2(v.x, v.y), pack2(v.z, v.w));
    }
    for (int i = gid; i < NQ4; i += stride) qzero[i] = make_uint4(0u, 0u, 0u, 0u);
    if (gid < BDIM * 2) stats[gid] = 0.0f;
    return;
  }
  // ---- GEMM planes ----
  const int l = tid & 63, wv = tid >> 6;
  const int m = tid >> 2, kq = (tid & 3) * 8;
  f32x4 acc[4] = {};
  if (bid < 40) {
    const int d0 = (bid & 7) * 64, t0 = (bid >> 3) * 64;
    for (int k0 = 0; k0 < 512; k0 += 32) {
      // stage text rows (zero-pad >=315) and A rows, hi/lo split in-register
      {
        int t = t0 + m;
        float4 v0 = make_float4(0.f, 0.f, 0.f, 0.f), v1 = v0;
        if (t < TDIM) {
          v0 = *(const float4*)(text + (size_t)t * DDIM + k0 + kq);
          v1 = *(const float4*)(text + (size_t)t * DDIM + k0 + kq + 4);
        }
        *(uint4*)(&Ahs[m * LDH + kq]) =
            make_uint4(pack2(v0.x, v0.y), pack2(v0.z, v0.w), pack2(v1.x, v1.y), pack2(v1.z, v1.w));
        *(uint4*)(&Als[m * LDH + kq]) =
            make_uint4(pack2(bfres(v0.x), bfres(v0.y)), pack2(bfres(v0.z), bfres(v0.w)),
                       pack2(bfres(v1.x), bfres(v1.y)), pack2(bfres(v1.z), bfres(v1.w)));
        float4 w0 = *(const float4*)(A + (size_t)(d0 + m) * DDIM + k0 + kq);
        float4 w1 = *(const float4*)(A + (size_t)(d0 + m) * DDIM + k0 + kq + 4);
        *(uint4*)(&Bhs[m * LDH + kq]) =
            make_uint4(pack2(w0.x, w0.y), pack2(w0.z, w0.w), pack2(w1.x, w1.y), pack2(w1.z, w1.w));
        *(uint4*)(&Bls[m * LDH + kq]) =
            make_uint4(pack2(bfres(w0.x), bfres(w0.y)), pack2(bfres(w0.z), bfres(w0.w)),
                       pack2(bfres(w1.x), bfres(w1.y)), pack2(bfres(w1.z), bfres(w1.w)));
      }
      __syncthreads();
      bf16x8 ah = *(const bf16x8*)(&Ahs[(wv * 16 + (l & 15)) * LDH + (l >> 4) * 8]);
      bf16x8 al = *(const bf16x8*)(&Als[(wv * 16 + (l & 15)) * LDH + (l >> 4) * 8]);
#pragma unroll
      for (int c = 0; c < 4; ++c) {
        bf16x8 bh_ = *(const bf16x8*)(&Bhs[(c * 16 + (l & 15)) * LDH + (l >> 4) * 8]);
        bf16x8 bl_ = *(const bf16x8*)(&Bls[(c * 16 + (l & 15)) * LDH + (l >> 4) * 8]);
        acc[c] = __builtin_amdgcn_mfma_f32_16x16x32_bf16(ah, bh_, acc[c], 0, 0, 0);
        acc[c] = __builtin_amdgcn_mfma_f32_16x16x32_bf16(ah, bl_, acc[c], 0, 0, 0);
        acc[c] = __builtin_amdgcn_mfma_f32_16x16x32_bf16(al, bh_, acc[c], 0, 0, 0);
      }
      __syncthreads();
    }
#pragma unroll
    for (int c = 0; c < 4; ++c)
#pragma unroll
      for (int r = 0; r < 4; ++r) {
        int t = t0 + wv * 16 + ((l >> 4) << 2) + r;  // pad rows (>=315) are exact zeros
        int d = d0 + c * 16 + (l & 15);
        tAb[(size_t)t * DDIM + d] = bf1(acc[c][r]);
      }
  } else {
    const int idx = bid - 40;
    const int h0 = (idx & 3) * 64, t0 = (idx >> 2) * 64;
    const float* Wb = Wh + DDIM * HDIM;  // bottom half, [k][h]
    const int col = tid & 31, g = tid >> 5;
    for (int k0 = 0; k0 < 512; k0 += 32) {
      {
        int t = t0 + m;
        float4 v0 = make_float4(0.f, 0.f, 0.f, 0.f), v1 = v0;
        if (t < TDIM) {
          v0 = *(const float4*)(text + (size_t)t * DDIM + k0 + kq);
          v1 = *(const float4*)(text + (size_t)t * DDIM + k0 + kq + 4);
        }
        *(uint4*)(&Ahs[m * LDH + kq]) =
            make_uint4(pack2(v0.x, v0.y), pack2(v0.z, v0.w), pack2(v1.x, v1.y), pack2(v1.z, v1.w));
        *(uint4*)(&Als[m * LDH + kq]) =
            make_uint4(pack2(bfres(v0.x), bfres(v0.y)), pack2(bfres(v0.z), bfres(v0.w)),
                       pack2(bfres(v1.x), bfres(v1.y)), pack2(bfres(v1.z), bfres(v1.w)));
        // Wh_bot: 8 floats at row (k0+col), cols h0+g*8.. ; scatter transposed
        float4 w0 = *(const float4*)(Wb + (size_t)(k0 + col) * HDIM + h0 + g * 8);
        float4 w1 = *(const float4*)(Wb + (size_t)(k0 + col) * HDIM + h0 + g * 8 + 4);
        float wr[8] = {w0.x, w0.y, w0.z, w0.w, w1.x, w1.y, w1.z, w1.w};
#pragma unroll
        for (int i = 0; i < 8; ++i) {
          Bhs[(g * 8 + i) * LDH + col] = bf1(wr[i]);
          Bls[(g * 8 + i) * LDH + col] = bf1(bfres(wr[i]));
        }
      }
      __syncthreads();
      bf16x8 ah = *(const bf16x8*)(&Ahs[(wv * 16 + (l & 15)) * LDH + (l >> 4) * 8]);
      bf16x8 al = *(const bf16x8*)(&Als[(wv * 16 + (l & 15)) * LDH + (l >> 4) * 8]);
#pragma unroll
      for (int c = 0; c < 4; ++c) {
        bf16x8 bh_ = *(const bf16x8*)(&Bhs[(c * 16 + (l & 15)) * LDH + (l >> 4) * 8]);
        bf16x8 bl_ = *(const bf16x8*)(&Bls[(c * 16 + (l & 15)) * LDH + (l >> 4) * 8]);
        acc[c] = __builtin_amdgcn_mfma_f32_16x16x32_bf16(ah, bh_, acc[c], 0, 0, 0);
        acc[c] = __builtin_amdgcn_mfma_f32_16x16x32_bf16(ah, bl_, acc[c], 0, 0, 0);
        acc[c] = __builtin_amdgcn_mfma_f32_16x16x32_bf16(al, bh_, acc[c], 0, 0, 0);
      }
      __syncthreads();
    }
#pragma unroll
    for (int c = 0; c < 4; ++c)
#pragma unroll
      for (int r = 0; r < 4; ++r) {
        int t = t0 + wv * 16 + ((l >> 4) << 2) + r;
        int h = h0 + c * 16 + (l & 15);
        TB[(size_t)t * HDIM + h] = acc[c][r] + bh[h];
      }
  }
}

// ---------------- K2: s[b][n][t] (fp16 out) + instnorm stats --------------------------------
// Grid (b, t, n): blockIdx.x = batch -> linear id % 8 == b % 8 -> all 35 blocks of a batch
// share one XCD; per-batch working set (Fb 0.41 MB + tAb 0.33 MB) is L2-resident.
__global__ __launch_bounds__(256) void k_s(const unsigned short* __restrict__ Fb,
                                           const unsigned short* __restrict__ tAb,
                                           __half* __restrict__ s, float* __restrict__ stats) {
  __shared__ unsigned short Abf[64 * LDH];
  __shared__ unsigned short Bbf[64 * LDH];
  __shared__ float red[8];
  const int tid = threadIdx.x, l = tid & 63, wv = tid >> 6;
  const int bz = blockIdx.x, t0 = blockIdx.y * 64, n0 = blockIdx.z * 64;
  const unsigned short* Fbb = Fb + (size_t)bz * NDIM * DDIM;
  __half* sb = s + (size_t)bz * NDIM * TPAD;
  f32x4 acc[4] = {};
  const int m = tid >> 2, kq = (tid & 3) * 8;
  for (int k0 = 0; k0 < 512; k0 += 32) {
    uint4 av = make_uint4(0, 0, 0, 0);
    int n = n0 + m;
    if (n < NDIM) av = *(const uint4*)(Fbb + (size_t)n * DDIM + k0 + kq);
    *(uint4*)(&Abf[m * LDH + kq]) = av;
    uint4 bv = *(const uint4*)(tAb + (size_t)(t0 + m) * DDIM + k0 + kq);
    *(uint4*)(&Bbf[m * LDH + kq]) = bv;
    __syncthreads();
    bf16x8 af = *(const bf16x8*)(&Abf[(wv * 16 + (l & 15)) * LDH + (l >> 4) * 8]);
#pragma unroll
    for (int c = 0; c < 4; ++c) {
      bf16x8 bf_ = *(const bf16x8*)(&Bbf[(c * 16 + (l & 15)) * LDH + (l >> 4) * 8]);
      acc[c] = __builtin_amdgcn_mfma_f32_16x16x32_bf16(af, bf_, acc[c], 0, 0, 0);
    }
    __syncthreads();
  }
  float lsum = 0.f, lsq = 0.f;
#pragma unroll
  for (int c = 0; c < 4; ++c)
#pragma unroll
    for (int r = 0; r < 4; ++r) {
      int n = n0 + wv * 16 + ((l >> 4) << 2) + r;
      int t = t0 + c * 16 + (l & 15);
      if (n < NDIM && t < TDIM) {
        float v = acc[c][r];
        sb[(size_t)n * TPAD + t] = __float2half(v);
        lsum += v;
        lsq = fmaf(v, v, lsq);
      }
    }
#pragma unroll
  for (int mm = 1; mm <= 32; mm <<= 1) {
    lsum += __shfl_xor(lsum, mm, 64);
    lsq += __shfl_xor(lsq, mm, 64);
  }
  if ((tid & 63) == 0) { red[wv * 2] = lsum; red[wv * 2 + 1] = lsq; }
  __syncthreads();
  if (tid == 0) {
    float S = red[0] + red[2] + red[4] + red[6];
    float Q = red[1] + red[3] + red[5] + red[7];
    atomicAdd(&stats[bz * 2], S);
    atomicAdd(&stats[bz * 2 + 1], Q);
  }
}

// ---------------- K3: multi-CU sinkhorn, tagged-pair single-RT exchange ---------------------
#define SBLK 8
#define SROWS 50
#define SRPW 10

__global__ __launch_bounds__(320, 1) void k_sinkhorn(const __half* __restrict__ sbuf,
                                                     const float* __restrict__ stats,
                                                     const float* __restrict__ gptr,
                                                     const float* __restrict__ bptr,
                                                     unsigned short* __restrict__ s1b,
                                                     ull* __restrict__ qpart) {
  __shared__ float qpl[5][320];   // per-wave own col partials
  __shared__ float qg[5][320];    // per-wave gathered cc-slice sums
  const int b = blockIdx.x, c = blockIdx.y;
  const int tid = threadIdx.x, wv = tid >> 6, l = tid & 63;
  const __half* S = sbuf + (size_t)b * NDIM * TPAD;
  unsigned short* S1 = s1b + (size_t)b * NDIM * TPAD;
  const float NT = 400.0f * 315.0f;
  const float mean = stats[2 * b] / NT;
  const float var = stats[2 * b + 1] / NT - mean * mean;
  const float inv = rsqrtf(var + 1e-5f);
  const float alpha = gptr[0] * inv;
  const float L2E = 1.4426950408889634f;
  const float a2 = alpha * L2E;
  const float d2 = (bptr[0] - mean * alpha) * L2E;
  const int r0 = c * SROWS + wv * SRPW;
  const float TOL = 1e-3f;
  const float TN_RATIO = 315.0f / 400.0f;

  float E0[SRPW], E1[SRPW], E2[SRPW], E3[SRPW], E4[SRPW];
#pragma unroll
  for (int j = 0; j < SRPW; ++j) {
    const __half* row = S + (size_t)(r0 + j) * TPAD;
    E0[j] = __builtin_amdgcn_exp2f(fmaf(__half2float(row[l]), a2, d2));
    E1[j] = __builtin_amdgcn_exp2f(fmaf(__half2float(row[64 + l]), a2, d2));
    E2[j] = __builtin_amdgcn_exp2f(fmaf(__half2float(row[128 + l]), a2, d2));
    E3[j] = __builtin_amdgcn_exp2f(fmaf(__half2float(row[192 + l]), a2, d2));
    E4[j] = (l < 59) ? __builtin_amdgcn_exp2f(fmaf(__half2float(row[256 + l]), a2, d2)) : 0.0f;
  }
  float w0 = 1.0f, w1 = 1.0f, w2 = 1.0f, w3 = 1.0f, w4 = (l < 59) ? 1.0f : 0.0f;
  float aj[SRPW];
#pragma unroll
  for (int j = 0; j < SRPW; ++j) aj[j] = 0.0f;

  bool fin = false;
  for (int it = 0; it < NITER; ++it) {
    float p[SRPW];
#pragma unroll
    for (int j = 0; j < SRPW; ++j) {
      float t = E4[j] * w4;
      t = fmaf(E3[j], w3, t);
      t = fmaf(E2[j], w2, t);
      t = fmaf(E1[j], w1, t);
      p[j] = fmaf(E0[j], w0, t);
    }
#pragma unroll
    for (int j = 0; j < SRPW; ++j) p[j] = dppadd<0x111, 0xf>(p[j]);
#pragma unroll
    for (int j = 0; j < SRPW; ++j) p[j] = dppadd<0x112, 0xf>(p[j]);
#pragma unroll
    for (int j = 0; j < SRPW; ++j) p[j] = dppadd<0x114, 0xf>(p[j]);
#pragma unroll
    for (int j = 0; j < SRPW; ++j) p[j] = dppadd<0x118, 0xf>(p[j]);
#pragma unroll
    for (int j = 0; j < SRPW; ++j) p[j] = dppadd<0x142, 0xa>(p[j]);
#pragma unroll
    for (int j = 0; j < SRPW; ++j) p[j] = dppadd<0x143, 0xc>(p[j]);
#pragma unroll
    for (int j = 0; j < SRPW; ++j) {
      float r = __builtin_amdgcn_rcpf(p[j]);
      aj[j] = __int_as_float(__builtin_amdgcn_readlane(__float_as_int(r), 63));
    }
    float q0 = 0.f, q1 = 0.f, q2 = 0.f, q3 = 0.f, q4 = 0.f;
#pragma unroll
    for (int j = 0; j < SRPW; ++j) {
      q0 = fmaf(E0[j], aj[j], q0);
      q1 = fmaf(E1[j], aj[j], q1);
      q2 = fmaf(E2[j], aj[j], q2);
      q3 = fmaf(E3[j], aj[j], q3);
      q4 = fmaf(E4[j], aj[j], q4);
    }
    qpl[wv][l] = q0;
    qpl[wv][64 + l] = q1;
    qpl[wv][128 + l] = q2;
    qpl[wv][192 + l] = q3;
    qpl[wv][256 + l] = q4;
    __syncthreads();
    const int par = it & 1;
    const unsigned tgt = (unsigned)(it + 1);
    ull* bufpar = qpart + ((size_t)par * BDIM + b) * (SBLK * 320);
    if (wv == 0) {
      ull* myp = bufpar + c * 320;
#pragma unroll
      for (int k = 0; k < 5; ++k) {
        int t = k * 64 + l;
        float sm = qpl[0][t] + qpl[1][t] + qpl[2][t] + qpl[3][t] + qpl[4][t];
        __hip_atomic_store(&myp[t], ((ull)tgt << 32) | (ull)__float_as_uint(sm),
                           __ATOMIC_RELAXED, __HIP_MEMORY_SCOPE_AGENT);
      }
    }
    {
      const int ncc = (wv < 3) ? 2 : 1;
      ull got[2][5];
      const int ccs[2] = {wv, wv + 5};
#pragma unroll
      for (int e = 0; e < 2; ++e)
        if (e < ncc && ccs[e] != c) {
#pragma unroll
          for (int k = 0; k < 5; ++k)
            got[e][k] = __hip_atomic_load(&bufpar[ccs[e] * 320 + k * 64 + l],
                                          __ATOMIC_RELAXED, __HIP_MEMORY_SCOPE_AGENT);
        }
      int guard = 0;
      for (;;) {
        bool ok = true;
#pragma unroll
        for (int e = 0; e < 2; ++e)
          if (e < ncc && ccs[e] != c) {
#pragma unroll
            for (int k = 0; k < 5; ++k)
              if ((unsigned)(got[e][k] >> 32) != tgt) {
                got[e][k] = __hip_atomic_load(&bufpar[ccs[e] * 320 + k * 64 + l],
                                              __ATOMIC_RELAXED, __HIP_MEMORY_SCOPE_AGENT);
                ok = false;
              }
          }
        if (ok) break;
        if (++guard > (1 << 20)) break;  // deadlock escape (should never trigger)
      }
      float part[5] = {0.f, 0.f, 0.f, 0.f, 0.f};
#pragma unroll
      for (int e = 0; e < 2; ++e)
        if (e < ncc) {
#pragma unroll
          for (int k = 0; k < 5; ++k) {
            int t = k * 64 + l;
            float v = (ccs[e] == c)
                          ? (qpl[0][t] + qpl[1][t] + qpl[2][t] + qpl[3][t] + qpl[4][t])
                          : __uint_as_float((unsigned)got[e][k]);
            part[k] += v;
          }
        }
#pragma unroll
      for (int k = 0; k < 5; ++k) qg[wv][k * 64 + l] = part[k];
    }
    __syncthreads();
    const float Q0 = qg[0][l] + qg[1][l] + qg[2][l] + qg[3][l] + qg[4][l];
    const float Q1 = qg[0][64 + l] + qg[1][64 + l] + qg[2][64 + l] + qg[3][64 + l] + qg[4][64 + l];
    const float Q2 =
        qg[0][128 + l] + qg[1][128 + l] + qg[2][128 + l] + qg[3][128 + l] + qg[4][128 + l];
    const float Q3 =
        qg[0][192 + l] + qg[1][192 + l] + qg[2][192 + l] + qg[3][192 + l] + qg[4][192 + l];
    const float Q4 =
        qg[0][256 + l] + qg[1][256 + l] + qg[2][256 + l] + qg[3][256 + l] + qg[4][256 + l];
    float r = fabsf(fmaf(Q0 * w0, TN_RATIO, -1.0f));
    r = fmaxf(r, fabsf(fmaf(Q1 * w1, TN_RATIO, -1.0f)));
    r = fmaxf(r, fabsf(fmaf(Q2 * w2, TN_RATIO, -1.0f)));
    r = fmaxf(r, fabsf(fmaf(Q3 * w3, TN_RATIO, -1.0f)));
    if (l < 59) r = fmaxf(r, fabsf(fmaf(Q4 * w4, TN_RATIO, -1.0f)));
    w0 = __builtin_amdgcn_rcpf(Q0);
    w1 = __builtin_amdgcn_rcpf(Q1);
    w2 = __builtin_amdgcn_rcpf(Q2);
    w3 = __builtin_amdgcn_rcpf(Q3);
    if (l < 59) w4 = __builtin_amdgcn_rcpf(Q4);
    if (fin) break;
    r = dppmax<0x111, 0xf>(r);
    r = dppmax<0x112, 0xf>(r);
    r = dppmax<0x114, 0xf>(r);
    r = dppmax<0x118, 0xf>(r);
    r = dppmax<0x142, 0xa>(r);
    r = dppmax<0x143, 0xc>(r);
    const float resid = __int_as_float(__builtin_amdgcn_readlane(__float_as_int(r), 63));
    fin = (resid < TOL) || (it == NITER - 2);
  }

#pragma unroll
  for (int j = 0; j < SRPW; ++j) {
    unsigned short* row = S1 + (size_t)(r0 + j) * TPAD;
    const float a = aj[j];
    row[l] = bf1(a * E0[j] * w0);
    row[64 + l] = bf1(a * E1[j] * w1);
    row[128 + l] = bf1(a * E2[j] * w2);
    row[192 + l] = bf1(a * E3[j] * w3);
    row[256 + l] = (l < 59) ? bf1(a * E4[j] * w4) : (unsigned short)0;
  }
}

// ---------------- K4: f1[b][t][d] = sum_n s1[b][n][t] * F[b][n][d]  (TN bf16 MFMA) ----------
// Grid (b, d, t): batch-major for XCD/L2 residency (per-batch set: s1 0.41 + Fb 0.41 MB).
__global__ __launch_bounds__(256) void k_f1(const unsigned short* __restrict__ s1b,
                                            const unsigned short* __restrict__ Fb,
                                            unsigned short* __restrict__ f1b) {
  __shared__ unsigned short Abf[64 * LDH];  // [t][n]
  __shared__ unsigned short Bbf[64 * LDH];  // [d][n]
  const int tid = threadIdx.x, l = tid & 63, wv = tid >> 6;
  const int bz = blockIdx.x, d0 = blockIdx.y * 64, t0 = blockIdx.z * 64;
  const unsigned short* sb = s1b + (size_t)bz * NDIM * TPAD;
  const unsigned short* Fbb = Fb + (size_t)bz * NDIM * DDIM;
  unsigned short* out = f1b + (size_t)bz * TDIM * DDIM;
  f32x4 acc[4] = {};
  const int col = tid & 31, g = tid >> 5;
  for (int k0 = 0; k0 < 416; k0 += 32) {
    int n = k0 + col;
    uint4 av = make_uint4(0, 0, 0, 0), bv = av;
    if (n < NDIM) {
      av = *(const uint4*)(sb + (size_t)n * TPAD + t0 + g * 8);
      bv = *(const uint4*)(Fbb + (size_t)n * DDIM + d0 + g * 8);
    }
    unsigned short ah[8], bh8[8];
    *(uint4*)ah = av;
    *(uint4*)bh8 = bv;
#pragma unroll
    for (int i = 0; i < 8; ++i) {
      Abf[(g * 8 + i) * LDH + col] = ah[i];
      Bbf[(g * 8 + i) * LDH + col] = bh8[i];
    }
    __syncthreads();
    bf16x8 af = *(const bf16x8*)(&Abf[(wv * 16 + (l & 15)) * LDH + (l >> 4) * 8]);
#pragma unroll
    for (int c = 0; c < 4; ++c) {
      bf16x8 bf_ = *(const bf16x8*)(&Bbf[(c * 16 + (l & 15)) * LDH + (l >> 4) * 8]);
      acc[c] = __builtin_amdgcn_mfma_f32_16x16x32_bf16(af, bf_, acc[c], 0, 0, 0);
    }
    __syncthreads();
  }
#pragma unroll
  for (int c = 0; c < 4; ++c)
#pragma unroll
    for (int r = 0; r < 4; ++r) {
      int t = t0 + wv * 16 + ((l >> 4) << 2) + r;
      int d = d0 + c * 16 + (l & 15);
      if (t < TDIM) out[(size_t)t * DDIM + d] = bf1(acc[c][r]);
    }
}

// ---------------- K5: fused h + pred, single pass over all 256 hidden -----------------------
// Tile 64 rows x 256 j: full row-sum completes in-wave -> direct store (no atomics, no
// out zero-init), f1b read once.
__global__ __launch_bounds__(256) void k_hp(const unsigned short* __restrict__ f1b,
                                            const unsigned short* __restrict__ Whb,
                                            const float* __restrict__ TB,
                                            const float* __restrict__ Wo,
                                            const float* __restrict__ bo,
                                            float* __restrict__ out) {
  __shared__ unsigned short Abf[64 * LDH];   // [r][k]
  __shared__ unsigned short Bbf[256 * LDH];  // [j][k]
  __shared__ float Wos[256];
  const int tid = threadIdx.x, l = tid & 63, wv = tid >> 6;
  const int r0 = blockIdx.x * 64;
  const int RTOT = BDIM * TDIM;  // 10080
  Wos[tid] = Wo[tid];
  f32x4 acc[16] = {};
  const int m = tid >> 2, kq = (tid & 3) * 8;
  const int col = tid & 31, g = tid >> 5;
  for (int k0 = 0; k0 < 512; k0 += 32) {
    uint4 av = make_uint4(0, 0, 0, 0);
    int r = r0 + m;
    if (r < RTOT) av = *(const uint4*)(f1b + (size_t)r * DDIM + k0 + kq);
    *(uint4*)(&Abf[m * LDH + kq]) = av;
#pragma unroll
    for (int p = 0; p < 4; ++p) {
      uint4 bv = *(const uint4*)(Whb + (size_t)(k0 + col) * HDIM + p * 64 + g * 8);
      unsigned short bh8[8];
      *(uint4*)bh8 = bv;
#pragma unroll
      for (int i = 0; i < 8; ++i) Bbf[(p * 64 + g * 8 + i) * LDH + col] = bh8[i];
    }
    __syncthreads();
    bf16x8 af = *(const bf16x8*)(&Abf[(wv * 16 + (l & 15)) * LDH + (l >> 4) * 8]);
#pragma unroll
    for (int c = 0; c < 16; ++c) {
      bf16x8 bf_ = *(const bf16x8*)(&Bbf[(c * 16 + (l & 15)) * LDH + (l >> 4) * 8]);
      acc[c] = __builtin_amdgcn_mfma_f32_16x16x32_bf16(af, bf_, acc[c], 0, 0, 0);
    }
    __syncthreads();
  }
  int tmod[4];
#pragma unroll
  for (int r = 0; r < 4; ++r) {
    int rr = r0 + wv * 16 + ((l >> 4) << 2) + r;
    tmod[r] = rr % TDIM;
  }
  float part[4] = {0.f, 0.f, 0.f, 0.f};
#pragma unroll
  for (int c = 0; c < 16; ++c) {
    int jl = c * 16 + (l & 15);
    float woc = Wos[jl];
#pragma unroll
    for (int r = 0; r < 4; ++r) {
      float v = acc[c][r] + TB[(size_t)tmod[r] * HDIM + jl];
      part[r] = fmaf(fmaxf(v, 0.f), woc, part[r]);
    }
  }
#pragma unroll
  for (int r = 0; r < 4; ++r) part[r] = dppadd<0x111, 0xf>(part[r]);
#pragma unroll
  for (int r = 0; r < 4; ++r) part[r] = dppadd<0x112, 0xf>(part[r]);
#pragma unroll
  for (int r = 0; r < 4; ++r) part[r] = dppadd<0x114, 0xf>(part[r]);
#pragma unroll
  for (int r = 0; r < 4; ++r) part[r] = dppadd<0x118, 0xf>(part[r]);
  if ((l & 15) == 15) {
    const float base = bo[0];
#pragma unroll
    for (int r = 0; r < 4; ++r) {
      int rr = r0 + wv * 16 + ((l >> 4) << 2) + r;
      if (rr < RTOT) out[rr] = part[r] + base;
    }
  }
}

// ---------------- launch ----------------
extern "C" void kernel_launch(void* const* d_in, const int* in_sizes, int n_in,
                              void* d_out, int out_size, void* d_ws, size_t ws_size,
                              hipStream_t stream) {
  const float* F     = (const float*)d_in[0];
  const float* text  = (const float*)d_in[1];
  const float* A     = (const float*)d_in[2];
  const float* gamma = (const float*)d_in[3];
  const float* beta  = (const float*)d_in[4];
  const float* Wh    = (const float*)d_in[5];
  const float* bh    = (const float*)d_in[6];
  const float* Wo    = (const float*)d_in[7];
  const float* bo    = (const float*)d_in[8];
  float* out = (float*)d_out;
  char* ws = (char*)d_ws;
  unsigned short* tAb = (unsigned short*)(ws + OFS_TAB);
  float* TB    = (float*)(ws + OFS_TB);
  float* stats = (float*)(ws + OFS_STATS);
  unsigned short* Whb = (unsigned short*)(ws + OFS_WHB);
  __half* sbuf = (__half*)(ws + OFS_S);
  unsigned short* s1b = (unsigned short*)(ws + OFS_S1B);
  unsigned short* f1b = (unsigned short*)(ws + OFS_F1);
  unsigned short* Fb  = (unsigned short*)(ws + OFS_FB);
  ull* qpart = (ull*)(ws + OFS_QPART);

  k_prep<<<512, 256, 0, stream>>>(F, Wh, text, A, bh, Fb, Whb, tAb, TB, stats, (uint4*)qpart);
  k_s<<<dim3(32, 5, 7), 256, 0, stream>>>(Fb, tAb, sbuf, stats);
  k_sinkhorn<<<dim3(BDIM, SBLK), 320, 0, stream>>>(sbuf, stats, gamma, beta, s1b, qpart);
  k_f1<<<dim3(32, 8, 5), 256, 0, stream>>>(s1b, Fb, f1b);
  k_hp<<<dim3(158), 256, 0, stream>>>(f1b, Whb, TB, Wo, bo, out);
}

// Round 6
// 185.753 us; speedup vs baseline: 1.0570x; 1.0570x over previous
//
#include <hip/hip_runtime.h>
#include <hip/hip_fp16.h>

// Problem dims
#define BDIM 32
#define NDIM 400
#define TDIM 315
#define TPAD 320
#define DDIM 512
#define HDIM 256
#define NITER 100

// Workspace layout (bytes)
#define OFS_TAB   0u          // tAb bf16 [320][512] = 327680
#define OFS_TB    327680u     // TB f32 [320][256] = 327680
#define OFS_WHB   655616u     // Whb bf16 [512][256] = 262144
#define OFS_S1B   9240576u    // s1b bf16 [32][400][320] = 8192000
#define OFS_F1    17432576u   // f1b bf16 [32][315][512] = 10321920  (end 27754496)
#define OFS_FB    27754496u   // Fb bf16 [32][400][512] = 13107200  (end 40861696)
// k_sinkhorn scratch overlaps the f1b region (f1b is produced AFTER sinkhorn):
// qpart: [2 parity][32 b][8 c][320] iteration atoms + [32 b][8 c][2] stats atoms (ull each)
#define OFS_QPART (OFS_F1 + 4096u)
#define QSTATS    163840u     // ull offset of stats atoms within qpart

typedef __attribute__((ext_vector_type(8))) short bf16x8;
typedef __attribute__((ext_vector_type(4))) float f32x4;
typedef unsigned long long ull;

// ---------------- bf16 pack/unpack (RNE) ----------------
__device__ __forceinline__ unsigned rne_hi(float x) {
  unsigned u = __float_as_uint(x);
  u += 0x7fffu + ((u >> 16) & 1u);
  return u & 0xffff0000u;
}
__device__ __forceinline__ unsigned pack2(float lo, float hi) {
  return (rne_hi(lo) >> 16) | rne_hi(hi);
}
__device__ __forceinline__ unsigned short bf1(float x) { return (unsigned short)(rne_hi(x) >> 16); }
__device__ __forceinline__ float bfres(float x) {  // x - bf16(x), the lo part
  return x - __uint_as_float(rne_hi(x));
}

// ---------------- DPP wave reduce helpers (VALU pipe, no LDS) ----------------
template <int CTRL, int RMASK>
__device__ __forceinline__ float dppadd(float x) {
  int y = __builtin_amdgcn_update_dpp(0, __float_as_int(x), CTRL, RMASK, 0xf, true);
  return x + __int_as_float(y);
}
template <int CTRL, int RMASK>
__device__ __forceinline__ float dppmax(float x) {
  int y = __builtin_amdgcn_update_dpp(0, __float_as_int(x), CTRL, RMASK, 0xf, true);
  return fmaxf(x, __int_as_float(y));
}

#define LDH 40

// ---------------- K0: fused prep ------------------------------------------------------------
// blocks 0..39   : tA = text @ A^T  via bf16x3 split MFMA, fp32->hi/lo converted in-register
// blocks 40..59  : TB = text @ Wh_bot + bh, same split MFMA
// blocks 60..511 : grid-stride packing (Fb, Whb top) + zero-init (qpart tags)
__global__ __launch_bounds__(256) void k_prep(const float* __restrict__ F,
                                              const float* __restrict__ Wh,
                                              const float* __restrict__ text,
                                              const float* __restrict__ A,
                                              const float* __restrict__ bh,
                                              unsigned short* __restrict__ Fb,
                                              unsigned short* __restrict__ Whb,
                                              unsigned short* __restrict__ tAb,
                                              float* __restrict__ TB,
                                              uint4* __restrict__ qzero) {
  __shared__ unsigned short Ahs[64 * LDH], Als[64 * LDH];
  __shared__ unsigned short Bhs[64 * LDH], Bls[64 * LDH];
  const int bid = blockIdx.x, tid = threadIdx.x;
  if (bid >= 60) {
    // ---- packing plane ----
    const int NF4 = (BDIM * NDIM * DDIM) / 4;    // 1638400
    const int NW4 = (DDIM * HDIM) / 4;           // 32768 (top half of Wh)
    const int NQ4 = (2 * BDIM * 8 * 320 * 2 + BDIM * 8 * 2 * 2) / 4;  // 82176
    const int gid = (bid - 60) * 256 + tid;
    const int stride = 452 * 256;
    for (int i = gid; i < NF4; i += stride) {
      float4 v = ((const float4*)F)[i];
      ((uint2*)Fb)[i] = make_uint2(pack2(v.x, v.y), pack2(v.z, v.w));
    }
    for (int i = gid; i < NW4; i += stride) {
      float4 v = ((const float4*)Wh)[i];
      ((uint2*)Whb)[i] = make_uint2(pack2(v.x, v.y), pack2(v.z, v.w));
    }
    for (int i = gid; i < NQ4; i += stride) qzero[i] = make_uint4(0u, 0u, 0u, 0u);
    return;
  }
  // ---- GEMM planes ----
  const int l = tid & 63, wv = tid >> 6;
  const int m = tid >> 2, kq = (tid & 3) * 8;
  f32x4 acc[4] = {};
  if (bid < 40) {
    const int d0 = (bid & 7) * 64, t0 = (bid >> 3) * 64;
    for (int k0 = 0; k0 < 512; k0 += 32) {
      {
        int t = t0 + m;
        float4 v0 = make_float4(0.f, 0.f, 0.f, 0.f), v1 = v0;
        if (t < TDIM) {
          v0 = *(const float4*)(text + (size_t)t * DDIM + k0 + kq);
          v1 = *(const float4*)(text + (size_t)t * DDIM + k0 + kq + 4);
        }
        *(uint4*)(&Ahs[m * LDH + kq]) =
            make_uint4(pack2(v0.x, v0.y), pack2(v0.z, v0.w), pack2(v1.x, v1.y), pack2(v1.z, v1.w));
        *(uint4*)(&Als[m * LDH + kq]) =
            make_uint4(pack2(bfres(v0.x), bfres(v0.y)), pack2(bfres(v0.z), bfres(v0.w)),
                       pack2(bfres(v1.x), bfres(v1.y)), pack2(bfres(v1.z), bfres(v1.w)));
        float4 w0 = *(const float4*)(A + (size_t)(d0 + m) * DDIM + k0 + kq);
        float4 w1 = *(const float4*)(A + (size_t)(d0 + m) * DDIM + k0 + kq + 4);
        *(uint4*)(&Bhs[m * LDH + kq]) =
            make_uint4(pack2(w0.x, w0.y), pack2(w0.z, w0.w), pack2(w1.x, w1.y), pack2(w1.z, w1.w));
        *(uint4*)(&Bls[m * LDH + kq]) =
            make_uint4(pack2(bfres(w0.x), bfres(w0.y)), pack2(bfres(w0.z), bfres(w0.w)),
                       pack2(bfres(w1.x), bfres(w1.y)), pack2(bfres(w1.z), bfres(w1.w)));
      }
      __syncthreads();
      bf16x8 ah = *(const bf16x8*)(&Ahs[(wv * 16 + (l & 15)) * LDH + (l >> 4) * 8]);
      bf16x8 al = *(const bf16x8*)(&Als[(wv * 16 + (l & 15)) * LDH + (l >> 4) * 8]);
#pragma unroll
      for (int c = 0; c < 4; ++c) {
        bf16x8 bh_ = *(const bf16x8*)(&Bhs[(c * 16 + (l & 15)) * LDH + (l >> 4) * 8]);
        bf16x8 bl_ = *(const bf16x8*)(&Bls[(c * 16 + (l & 15)) * LDH + (l >> 4) * 8]);
        acc[c] = __builtin_amdgcn_mfma_f32_16x16x32_bf16(ah, bh_, acc[c], 0, 0, 0);
        acc[c] = __builtin_amdgcn_mfma_f32_16x16x32_bf16(ah, bl_, acc[c], 0, 0, 0);
        acc[c] = __builtin_amdgcn_mfma_f32_16x16x32_bf16(al, bh_, acc[c], 0, 0, 0);
      }
      __syncthreads();
    }
#pragma unroll
    for (int c = 0; c < 4; ++c)
#pragma unroll
      for (int r = 0; r < 4; ++r) {
        int t = t0 + wv * 16 + ((l >> 4) << 2) + r;  // pad rows (>=315) are exact zeros
        int d = d0 + c * 16 + (l & 15);
        tAb[(size_t)t * DDIM + d] = bf1(acc[c][r]);
      }
  } else {
    const int idx = bid - 40;
    const int h0 = (idx & 3) * 64, t0 = (idx >> 2) * 64;
    const float* Wb = Wh + DDIM * HDIM;  // bottom half, [k][h]
    const int col = tid & 31, g = tid >> 5;
    for (int k0 = 0; k0 < 512; k0 += 32) {
      {
        int t = t0 + m;
        float4 v0 = make_float4(0.f, 0.f, 0.f, 0.f), v1 = v0;
        if (t < TDIM) {
          v0 = *(const float4*)(text + (size_t)t * DDIM + k0 + kq);
          v1 = *(const float4*)(text + (size_t)t * DDIM + k0 + kq + 4);
        }
        *(uint4*)(&Ahs[m * LDH + kq]) =
            make_uint4(pack2(v0.x, v0.y), pack2(v0.z, v0.w), pack2(v1.x, v1.y), pack2(v1.z, v1.w));
        *(uint4*)(&Als[m * LDH + kq]) =
            make_uint4(pack2(bfres(v0.x), bfres(v0.y)), pack2(bfres(v0.z), bfres(v0.w)),
                       pack2(bfres(v1.x), bfres(v1.y)), pack2(bfres(v1.z), bfres(v1.w)));
        float4 w0 = *(const float4*)(Wb + (size_t)(k0 + col) * HDIM + h0 + g * 8);
        float4 w1 = *(const float4*)(Wb + (size_t)(k0 + col) * HDIM + h0 + g * 8 + 4);
        float wr[8] = {w0.x, w0.y, w0.z, w0.w, w1.x, w1.y, w1.z, w1.w};
#pragma unroll
        for (int i = 0; i < 8; ++i) {
          Bhs[(g * 8 + i) * LDH + col] = bf1(wr[i]);
          Bls[(g * 8 + i) * LDH + col] = bf1(bfres(wr[i]));
        }
      }
      __syncthreads();
      bf16x8 ah = *(const bf16x8*)(&Ahs[(wv * 16 + (l & 15)) * LDH + (l >> 4) * 8]);
      bf16x8 al = *(const bf16x8*)(&Als[(wv * 16 + (l & 15)) * LDH + (l >> 4) * 8]);
#pragma unroll
      for (int c = 0; c < 4; ++c) {
        bf16x8 bh_ = *(const bf16x8*)(&Bhs[(c * 16 + (l & 15)) * LDH + (l >> 4) * 8]);
        bf16x8 bl_ = *(const bf16x8*)(&Bls[(c * 16 + (l & 15)) * LDH + (l >> 4) * 8]);
        acc[c] = __builtin_amdgcn_mfma_f32_16x16x32_bf16(ah, bh_, acc[c], 0, 0, 0);
        acc[c] = __builtin_amdgcn_mfma_f32_16x16x32_bf16(ah, bl_, acc[c], 0, 0, 0);
        acc[c] = __builtin_amdgcn_mfma_f32_16x16x32_bf16(al, bh_, acc[c], 0, 0, 0);
      }
      __syncthreads();
    }
#pragma unroll
    for (int c = 0; c < 4; ++c)
#pragma unroll
      for (int r = 0; r < 4; ++r) {
        int t = t0 + wv * 16 + ((l >> 4) << 2) + r;
        int h = h0 + c * 16 + (l & 15);
        TB[(size_t)t * HDIM + h] = acc[c][r] + bh[h];
      }
  }
}

// ---------------- K3: fused s-GEMM + instnorm + sinkhorn ------------------------------------
// Grid (32, 8): block (b,c) owns rows c*50..c*50+49 of batch b. Phase 1 computes its S-tile
// = Fb[b, rows, :] @ tAb^T via bf16 MFMA (same lane mapping as the old k_s, proven) into LDS
// fp32 (no global s buffer). Stats via one tagged-pair exchange (tag=1, dedicated region);
// all blocks sum the 8 partials in fixed order -> identical mean/var bits. Then E from fp32
// LDS and the proven tagged-exchange iteration loop. 1 block/CU by LDS (grid=256=CUs).
#define SBLK 8
#define SROWS 50
#define SRPW 10

__global__ __launch_bounds__(320, 1) void k_sinkhorn(const unsigned short* __restrict__ Fb,
                                                     const unsigned short* __restrict__ tAb,
                                                     const float* __restrict__ gptr,
                                                     const float* __restrict__ bptr,
                                                     unsigned short* __restrict__ s1b,
                                                     ull* __restrict__ qpart) {
  __shared__ unsigned short Fch[64 * LDH];    // F rows chunk   [64][32]
  __shared__ unsigned short tACh[320 * LDH];  // tA rows chunk  [320][32]
  __shared__ float Sls[SROWS * 320];          // S-tile fp32
  __shared__ float qpl[5][320];               // per-wave own col partials
  __shared__ float qg[5][320];                // per-wave gathered cc-slice sums
  __shared__ float sred[16];
  const int b = blockIdx.x, c = blockIdx.y;
  const int tid = threadIdx.x, wv = tid >> 6, l = tid & 63;
  unsigned short* S1 = s1b + (size_t)b * NDIM * TPAD;
  const unsigned short* Fbb = Fb + (size_t)b * NDIM * DDIM + (size_t)c * SROWS * DDIM;
  const float TOL = 1e-3f;
  const float TN_RATIO = 315.0f / 400.0f;

  // ---- phase 1: S-tile MFMA (pattern verbatim from old k_s) ----
  f32x4 acc[16] = {};  // [tt][nt]
  {
    const int m = tid >> 2, kq = (tid & 3) * 8;
    for (int k0 = 0; k0 < 512; k0 += 32) {
      if (m < 64) {
        uint4 fv = make_uint4(0, 0, 0, 0);
        if (m < SROWS) fv = *(const uint4*)(Fbb + (size_t)m * DDIM + k0 + kq);
        *(uint4*)(&Fch[m * LDH + kq]) = fv;
      }
#pragma unroll
      for (int p = 0; p < 4; ++p) {
        int row = p * 80 + m;
        *(uint4*)(&tACh[row * LDH + kq]) = *(const uint4*)(tAb + (size_t)row * DDIM + k0 + kq);
      }
      __syncthreads();
      bf16x8 af[4];
#pragma unroll
      for (int nt = 0; nt < 4; ++nt)
        af[nt] = *(const bf16x8*)(&Fch[(nt * 16 + (l & 15)) * LDH + (l >> 4) * 8]);
#pragma unroll
      for (int tt = 0; tt < 4; ++tt) {
        bf16x8 bf_ = *(const bf16x8*)(&tACh[((wv * 4 + tt) * 16 + (l & 15)) * LDH + (l >> 4) * 8]);
#pragma unroll
        for (int nt = 0; nt < 4; ++nt)
          acc[tt * 4 + nt] = __builtin_amdgcn_mfma_f32_16x16x32_bf16(af[nt], bf_, acc[tt * 4 + nt], 0, 0, 0);
      }
      __syncthreads();
    }
  }
  // ---- write S-tile to LDS + local stats partial ----
  float ls = 0.f, lq = 0.f;
#pragma unroll
  for (int tt = 0; tt < 4; ++tt) {
    int t = (wv * 4 + tt) * 16 + (l & 15);
    bool tv = (t < TDIM);
#pragma unroll
    for (int nt = 0; nt < 4; ++nt)
#pragma unroll
      for (int r = 0; r < 4; ++r) {
        int n = nt * 16 + ((l >> 4) << 2) + r;
        if (n < SROWS && tv) {
          float v = acc[tt * 4 + nt][r];
          Sls[n * 320 + t] = v;
          ls += v;
          lq = fmaf(v, v, lq);
        }
      }
  }
#pragma unroll
  for (int mm = 1; mm <= 32; mm <<= 1) {
    ls += __shfl_xor(ls, mm, 64);
    lq += __shfl_xor(lq, mm, 64);
  }
  if (l == 0) { sred[wv] = ls; sred[8 + wv] = lq; }
  __syncthreads();
  // ---- stats exchange: publish 2 tagged atoms, gather 8 blocks x 2 (wave0) ----
  {
    ull* satoms = qpart + QSTATS;
    if (tid == 0) {
      float Ssum = sred[0] + sred[1] + sred[2] + sred[3] + sred[4];
      float Sq = sred[8] + sred[9] + sred[10] + sred[11] + sred[12];
      ull* mine = satoms + ((size_t)b * SBLK + c) * 2;
      __hip_atomic_store(&mine[0], (1ull << 32) | (ull)__float_as_uint(Ssum),
                         __ATOMIC_RELAXED, __HIP_MEMORY_SCOPE_AGENT);
      __hip_atomic_store(&mine[1], (1ull << 32) | (ull)__float_as_uint(Sq),
                         __ATOMIC_RELAXED, __HIP_MEMORY_SCOPE_AGENT);
    }
    if (wv == 0) {
      ull g = (1ull << 32);
      const ull* base = satoms + (size_t)b * SBLK * 2;
      if (l < 16) g = __hip_atomic_load(&base[l], __ATOMIC_RELAXED, __HIP_MEMORY_SCOPE_AGENT);
      int guard = 0;
      while (!((unsigned)(g >> 32) >= 1u)) {
        if (++guard > (1 << 20)) break;
        if (l < 16) g = __hip_atomic_load(&base[l], __ATOMIC_RELAXED, __HIP_MEMORY_SCOPE_AGENT);
      }
      // wait for ALL lanes' atoms
      for (;;) {
        if (__ballot((unsigned)(g >> 32) >= 1u) == ~0ull) break;
        if (l < 16 && (unsigned)(g >> 32) < 1u)
          g = __hip_atomic_load(&base[l], __ATOMIC_RELAXED, __HIP_MEMORY_SCOPE_AGENT);
      }
      if (l < 16) sred[l] = __uint_as_float((unsigned)g);
    }
  }
  __syncthreads();
  const float NT = 400.0f * 315.0f;
  const float Ssum_all = ((sred[0] + sred[2]) + (sred[4] + sred[6])) +
                         ((sred[8] + sred[10]) + (sred[12] + sred[14]));
  const float Sq_all = ((sred[1] + sred[3]) + (sred[5] + sred[7])) +
                       ((sred[9] + sred[11]) + (sred[13] + sred[15]));
  const float mean = Ssum_all / NT;
  const float var = Sq_all / NT - mean * mean;
  const float inv = rsqrtf(var + 1e-5f);
  const float alpha = gptr[0] * inv;
  const float L2E = 1.4426950408889634f;
  const float a2 = alpha * L2E;
  const float d2 = (bptr[0] - mean * alpha) * L2E;
  const int r0 = c * SROWS + wv * SRPW;

  // ---- E = exp(instnorm(S)) from fp32 LDS ----
  float E0[SRPW], E1[SRPW], E2[SRPW], E3[SRPW], E4[SRPW];
#pragma unroll
  for (int j = 0; j < SRPW; ++j) {
    const float* row = Sls + (wv * SRPW + j) * 320;
    E0[j] = __builtin_amdgcn_exp2f(fmaf(row[l], a2, d2));
    E1[j] = __builtin_amdgcn_exp2f(fmaf(row[64 + l], a2, d2));
    E2[j] = __builtin_amdgcn_exp2f(fmaf(row[128 + l], a2, d2));
    E3[j] = __builtin_amdgcn_exp2f(fmaf(row[192 + l], a2, d2));
    E4[j] = (l < 59) ? __builtin_amdgcn_exp2f(fmaf(row[256 + l], a2, d2)) : 0.0f;
  }
  float w0 = 1.0f, w1 = 1.0f, w2 = 1.0f, w3 = 1.0f, w4 = (l < 59) ? 1.0f : 0.0f;
  float aj[SRPW];
#pragma unroll
  for (int j = 0; j < SRPW; ++j) aj[j] = 0.0f;

  bool fin = false;
  for (int it = 0; it < NITER; ++it) {
    float p[SRPW];
#pragma unroll
    for (int j = 0; j < SRPW; ++j) {
      float t = E4[j] * w4;
      t = fmaf(E3[j], w3, t);
      t = fmaf(E2[j], w2, t);
      t = fmaf(E1[j], w1, t);
      p[j] = fmaf(E0[j], w0, t);
    }
#pragma unroll
    for (int j = 0; j < SRPW; ++j) p[j] = dppadd<0x111, 0xf>(p[j]);
#pragma unroll
    for (int j = 0; j < SRPW; ++j) p[j] = dppadd<0x112, 0xf>(p[j]);
#pragma unroll
    for (int j = 0; j < SRPW; ++j) p[j] = dppadd<0x114, 0xf>(p[j]);
#pragma unroll
    for (int j = 0; j < SRPW; ++j) p[j] = dppadd<0x118, 0xf>(p[j]);
#pragma unroll
    for (int j = 0; j < SRPW; ++j) p[j] = dppadd<0x142, 0xa>(p[j]);
#pragma unroll
    for (int j = 0; j < SRPW; ++j) p[j] = dppadd<0x143, 0xc>(p[j]);
#pragma unroll
    for (int j = 0; j < SRPW; ++j) {
      float r = __builtin_amdgcn_rcpf(p[j]);
      aj[j] = __int_as_float(__builtin_amdgcn_readlane(__float_as_int(r), 63));
    }
    float q0 = 0.f, q1 = 0.f, q2 = 0.f, q3 = 0.f, q4 = 0.f;
#pragma unroll
    for (int j = 0; j < SRPW; ++j) {
      q0 = fmaf(E0[j], aj[j], q0);
      q1 = fmaf(E1[j], aj[j], q1);
      q2 = fmaf(E2[j], aj[j], q2);
      q3 = fmaf(E3[j], aj[j], q3);
      q4 = fmaf(E4[j], aj[j], q4);
    }
    qpl[wv][l] = q0;
    qpl[wv][64 + l] = q1;
    qpl[wv][128 + l] = q2;
    qpl[wv][192 + l] = q3;
    qpl[wv][256 + l] = q4;
    __syncthreads();
    const int par = it & 1;
    const unsigned tgt = (unsigned)(it + 1);
    ull* bufpar = qpart + ((size_t)par * BDIM + b) * (SBLK * 320);
    if (wv == 0) {
      ull* myp = bufpar + c * 320;
#pragma unroll
      for (int k = 0; k < 5; ++k) {
        int t = k * 64 + l;
        float sm = qpl[0][t] + qpl[1][t] + qpl[2][t] + qpl[3][t] + qpl[4][t];
        __hip_atomic_store(&myp[t], ((ull)tgt << 32) | (ull)__float_as_uint(sm),
                           __ATOMIC_RELAXED, __HIP_MEMORY_SCOPE_AGENT);
      }
    }
    {
      const int ncc = (wv < 3) ? 2 : 1;
      ull got[2][5];
      const int ccs[2] = {wv, wv + 5};
#pragma unroll
      for (int e = 0; e < 2; ++e)
        if (e < ncc && ccs[e] != c) {
#pragma unroll
          for (int k = 0; k < 5; ++k)
            got[e][k] = __hip_atomic_load(&bufpar[ccs[e] * 320 + k * 64 + l],
                                          __ATOMIC_RELAXED, __HIP_MEMORY_SCOPE_AGENT);
        }
      int guard = 0;
      for (;;) {
        bool ok = true;
#pragma unroll
        for (int e = 0; e < 2; ++e)
          if (e < ncc && ccs[e] != c) {
#pragma unroll
            for (int k = 0; k < 5; ++k)
              if ((unsigned)(got[e][k] >> 32) != tgt) {
                got[e][k] = __hip_atomic_load(&bufpar[ccs[e] * 320 + k * 64 + l],
                                              __ATOMIC_RELAXED, __HIP_MEMORY_SCOPE_AGENT);
                ok = false;
              }
          }
        if (ok) break;
        if (++guard > (1 << 20)) break;  // deadlock escape (should never trigger)
      }
      float part[5] = {0.f, 0.f, 0.f, 0.f, 0.f};
#pragma unroll
      for (int e = 0; e < 2; ++e)
        if (e < ncc) {
#pragma unroll
          for (int k = 0; k < 5; ++k) {
            int t = k * 64 + l;
            float v = (ccs[e] == c)
                          ? (qpl[0][t] + qpl[1][t] + qpl[2][t] + qpl[3][t] + qpl[4][t])
                          : __uint_as_float((unsigned)got[e][k]);
            part[k] += v;
          }
        }
#pragma unroll
      for (int k = 0; k < 5; ++k) qg[wv][k * 64 + l] = part[k];
    }
    __syncthreads();
    const float Q0 = qg[0][l] + qg[1][l] + qg[2][l] + qg[3][l] + qg[4][l];
    const float Q1 = qg[0][64 + l] + qg[1][64 + l] + qg[2][64 + l] + qg[3][64 + l] + qg[4][64 + l];
    const float Q2 =
        qg[0][128 + l] + qg[1][128 + l] + qg[2][128 + l] + qg[3][128 + l] + qg[4][128 + l];
    const float Q3 =
        qg[0][192 + l] + qg[1][192 + l] + qg[2][192 + l] + qg[3][192 + l] + qg[4][192 + l];
    const float Q4 =
        qg[0][256 + l] + qg[1][256 + l] + qg[2][256 + l] + qg[3][256 + l] + qg[4][256 + l];
    float r = fabsf(fmaf(Q0 * w0, TN_RATIO, -1.0f));
    r = fmaxf(r, fabsf(fmaf(Q1 * w1, TN_RATIO, -1.0f)));
    r = fmaxf(r, fabsf(fmaf(Q2 * w2, TN_RATIO, -1.0f)));
    r = fmaxf(r, fabsf(fmaf(Q3 * w3, TN_RATIO, -1.0f)));
    if (l < 59) r = fmaxf(r, fabsf(fmaf(Q4 * w4, TN_RATIO, -1.0f)));
    w0 = __builtin_amdgcn_rcpf(Q0);
    w1 = __builtin_amdgcn_rcpf(Q1);
    w2 = __builtin_amdgcn_rcpf(Q2);
    w3 = __builtin_amdgcn_rcpf(Q3);
    if (l < 59) w4 = __builtin_amdgcn_rcpf(Q4);
    if (fin) break;
    r = dppmax<0x111, 0xf>(r);
    r = dppmax<0x112, 0xf>(r);
    r = dppmax<0x114, 0xf>(r);
    r = dppmax<0x118, 0xf>(r);
    r = dppmax<0x142, 0xa>(r);
    r = dppmax<0x143, 0xc>(r);
    const float resid = __int_as_float(__builtin_amdgcn_readlane(__float_as_int(r), 63));
    fin = (resid < TOL) || (it == NITER - 2);
  }

#pragma unroll
  for (int j = 0; j < SRPW; ++j) {
    unsigned short* row = S1 + (size_t)(r0 + j) * TPAD;
    const float a = aj[j];
    row[l] = bf1(a * E0[j] * w0);
    row[64 + l] = bf1(a * E1[j] * w1);
    row[128 + l] = bf1(a * E2[j] * w2);
    row[192 + l] = bf1(a * E3[j] * w3);
    row[256 + l] = (l < 59) ? bf1(a * E4[j] * w4) : (unsigned short)0;
  }
}

// ---------------- K4: f1[b][t][d] = sum_n s1[b][n][t] * F[b][n][d]  (TN bf16 MFMA) ----------
__global__ __launch_bounds__(256) void k_f1(const unsigned short* __restrict__ s1b,
                                            const unsigned short* __restrict__ Fb,
                                            unsigned short* __restrict__ f1b) {
  __shared__ unsigned short Abf[64 * LDH];  // [t][n]
  __shared__ unsigned short Bbf[64 * LDH];  // [d][n]
  const int tid = threadIdx.x, l = tid & 63, wv = tid >> 6;
  const int bz = blockIdx.x, d0 = blockIdx.y * 64, t0 = blockIdx.z * 64;
  const unsigned short* sb = s1b + (size_t)bz * NDIM * TPAD;
  const unsigned short* Fbb = Fb + (size_t)bz * NDIM * DDIM;
  unsigned short* out = f1b + (size_t)bz * TDIM * DDIM;
  f32x4 acc[4] = {};
  const int col = tid & 31, g = tid >> 5;
  for (int k0 = 0; k0 < 416; k0 += 32) {
    int n = k0 + col;
    uint4 av = make_uint4(0, 0, 0, 0), bv = av;
    if (n < NDIM) {
      av = *(const uint4*)(sb + (size_t)n * TPAD + t0 + g * 8);
      bv = *(const uint4*)(Fbb + (size_t)n * DDIM + d0 + g * 8);
    }
    unsigned short ah[8], bh8[8];
    *(uint4*)ah = av;
    *(uint4*)bh8 = bv;
#pragma unroll
    for (int i = 0; i < 8; ++i) {
      Abf[(g * 8 + i) * LDH + col] = ah[i];
      Bbf[(g * 8 + i) * LDH + col] = bh8[i];
    }
    __syncthreads();
    bf16x8 af = *(const bf16x8*)(&Abf[(wv * 16 + (l & 15)) * LDH + (l >> 4) * 8]);
#pragma unroll
    for (int c = 0; c < 4; ++c) {
      bf16x8 bf_ = *(const bf16x8*)(&Bbf[(c * 16 + (l & 15)) * LDH + (l >> 4) * 8]);
      acc[c] = __builtin_amdgcn_mfma_f32_16x16x32_bf16(af, bf_, acc[c], 0, 0, 0);
    }
    __syncthreads();
  }
#pragma unroll
  for (int c = 0; c < 4; ++c)
#pragma unroll
    for (int r = 0; r < 4; ++r) {
      int t = t0 + wv * 16 + ((l >> 4) << 2) + r;
      int d = d0 + c * 16 + (l & 15);
      if (t < TDIM) out[(size_t)t * DDIM + d] = bf1(acc[c][r]);
    }
}

// ---------------- K5: fused h + pred, single pass over all 256 hidden -----------------------
__global__ __launch_bounds__(256) void k_hp(const unsigned short* __restrict__ f1b,
                                            const unsigned short* __restrict__ Whb,
                                            const float* __restrict__ TB,
                                            const float* __restrict__ Wo,
                                            const float* __restrict__ bo,
                                            float* __restrict__ out) {
  __shared__ unsigned short Abf[64 * LDH];   // [r][k]
  __shared__ unsigned short Bbf[256 * LDH];  // [j][k]
  __shared__ float Wos[256];
  const int tid = threadIdx.x, l = tid & 63, wv = tid >> 6;
  const int r0 = blockIdx.x * 64;
  const int RTOT = BDIM * TDIM;  // 10080
  Wos[tid] = Wo[tid];
  f32x4 acc[16] = {};
  const int m = tid >> 2, kq = (tid & 3) * 8;
  const int col = tid & 31, g = tid >> 5;
  for (int k0 = 0; k0 < 512; k0 += 32) {
    uint4 av = make_uint4(0, 0, 0, 0);
    int r = r0 + m;
    if (r < RTOT) av = *(const uint4*)(f1b + (size_t)r * DDIM + k0 + kq);
    *(uint4*)(&Abf[m * LDH + kq]) = av;
#pragma unroll
    for (int p = 0; p < 4; ++p) {
      uint4 bv = *(const uint4*)(Whb + (size_t)(k0 + col) * HDIM + p * 64 + g * 8);
      unsigned short bh8[8];
      *(uint4*)bh8 = bv;
#pragma unroll
      for (int i = 0; i < 8; ++i) Bbf[(p * 64 + g * 8 + i) * LDH + col] = bh8[i];
    }
    __syncthreads();
    bf16x8 af = *(const bf16x8*)(&Abf[(wv * 16 + (l & 15)) * LDH + (l >> 4) * 8]);
#pragma unroll
    for (int c = 0; c < 16; ++c) {
      bf16x8 bf_ = *(const bf16x8*)(&Bbf[(c * 16 + (l & 15)) * LDH + (l >> 4) * 8]);
      acc[c] = __builtin_amdgcn_mfma_f32_16x16x32_bf16(af, bf_, acc[c], 0, 0, 0);
    }
    __syncthreads();
  }
  int tmod[4];
#pragma unroll
  for (int r = 0; r < 4; ++r) {
    int rr = r0 + wv * 16 + ((l >> 4) << 2) + r;
    tmod[r] = rr % TDIM;
  }
  float part[4] = {0.f, 0.f, 0.f, 0.f};
#pragma unroll
  for (int c = 0; c < 16; ++c) {
    int jl = c * 16 + (l & 15);
    float woc = Wos[jl];
#pragma unroll
    for (int r = 0; r < 4; ++r) {
      float v = acc[c][r] + TB[(size_t)tmod[r] * HDIM + jl];
      part[r] = fmaf(fmaxf(v, 0.f), woc, part[r]);
    }
  }
#pragma unroll
  for (int r = 0; r < 4; ++r) part[r] = dppadd<0x111, 0xf>(part[r]);
#pragma unroll
  for (int r = 0; r < 4; ++r) part[r] = dppadd<0x112, 0xf>(part[r]);
#pragma unroll
  for (int r = 0; r < 4; ++r) part[r] = dppadd<0x114, 0xf>(part[r]);
#pragma unroll
  for (int r = 0; r < 4; ++r) part[r] = dppadd<0x118, 0xf>(part[r]);
  if ((l & 15) == 15) {
    const float base = bo[0];
#pragma unroll
    for (int r = 0; r < 4; ++r) {
      int rr = r0 + wv * 16 + ((l >> 4) << 2) + r;
      if (rr < RTOT) out[rr] = part[r] + base;
    }
  }
}

// ---------------- launch ----------------
extern "C" void kernel_launch(void* const* d_in, const int* in_sizes, int n_in,
                              void* d_out, int out_size, void* d_ws, size_t ws_size,
                              hipStream_t stream) {
  const float* F     = (const float*)d_in[0];
  const float* text  = (const float*)d_in[1];
  const float* A     = (const float*)d_in[2];
  const float* gamma = (const float*)d_in[3];
  const float* beta  = (const float*)d_in[4];
  const float* Wh    = (const float*)d_in[5];
  const float* bh    = (const float*)d_in[6];
  const float* Wo    = (const float*)d_in[7];
  const float* bo    = (const float*)d_in[8];
  float* out = (float*)d_out;
  char* ws = (char*)d_ws;
  unsigned short* tAb = (unsigned short*)(ws + OFS_TAB);
  float* TB    = (float*)(ws + OFS_TB);
  unsigned short* Whb = (unsigned short*)(ws + OFS_WHB);
  unsigned short* s1b = (unsigned short*)(ws + OFS_S1B);
  unsigned short* f1b = (unsigned short*)(ws + OFS_F1);
  unsigned short* Fb  = (unsigned short*)(ws + OFS_FB);
  ull* qpart = (ull*)(ws + OFS_QPART);

  k_prep<<<512, 256, 0, stream>>>(F, Wh, text, A, bh, Fb, Whb, tAb, TB, (uint4*)qpart);
  k_sinkhorn<<<dim3(BDIM, SBLK), 320, 0, stream>>>(Fb, tAb, gamma, beta, s1b, qpart);
  k_f1<<<dim3(32, 8, 5), 256, 0, stream>>>(s1b, Fb, f1b);
  k_hp<<<dim3(158), 256, 0, stream>>>(f1b, Whb, TB, Wo, bo, out);
}

// Round 9
// 176.095 us; speedup vs baseline: 1.1150x; 1.0548x over previous
//
#include <hip/hip_runtime.h>
#include <hip/hip_fp16.h>

// Problem dims
#define BDIM 32
#define NDIM 400
#define TDIM 315
#define TPAD 320
#define DDIM 512
#define HDIM 256
#define NITER 100

// Workspace layout (bytes) — total 29,495,296 (ws is ≥256 MiB per harness fill size)
#define OFS_TAB   0u           // tAb bf16 [320][512] = 327680
#define OFS_TB    327680u      // TB f32 [320][256] = 327680            (end 655360)
#define OFS_WHT   655360u      // WhbT bf16 [256 j][512 k] = 262144     (end 917504)
#define OFS_QPART 917504u      // qpart ull: [2][32][8][320] = 1310720 + stats [32][8][2] = 4096 (end 2232320)
#define QSTATS    163840u      // ull offset of stats atoms within qpart
#define OFS_S1T   2232320u     // s1T bf16 [32][8][320][64] = 10485760  (end 12718080)
#define OFS_FBT   12718080u    // FbT bf16 [32][8][512][64] = 16777216  (end 29495296)

typedef __attribute__((ext_vector_type(8))) short bf16x8;
typedef __attribute__((ext_vector_type(4))) float f32x4;
typedef unsigned long long ull;

// ---------------- bf16 pack/unpack (RNE) ----------------
__device__ __forceinline__ unsigned rne_hi(float x) {
  unsigned u = __float_as_uint(x);
  u += 0x7fffu + ((u >> 16) & 1u);
  return u & 0xffff0000u;
}
__device__ __forceinline__ unsigned pack2(float lo, float hi) {
  return (rne_hi(lo) >> 16) | rne_hi(hi);
}
__device__ __forceinline__ unsigned short bf1(float x) { return (unsigned short)(rne_hi(x) >> 16); }
__device__ __forceinline__ float bfres(float x) {  // x - bf16(x), the lo part
  return x - __uint_as_float(rne_hi(x));
}

// ---------------- DPP wave reduce helpers (VALU pipe, no LDS) ----------------
template <int CTRL, int RMASK>
__device__ __forceinline__ float dppadd(float x) {
  int y = __builtin_amdgcn_update_dpp(0, __float_as_int(x), CTRL, RMASK, 0xf, true);
  return x + __int_as_float(y);
}
template <int CTRL, int RMASK>
__device__ __forceinline__ float dppmax(float x) {
  int y = __builtin_amdgcn_update_dpp(0, __float_as_int(x), CTRL, RMASK, 0xf, true);
  return fmaxf(x, __int_as_float(y));
}

#define LDH 40
#define SBLK 8
#define SROWS 50
#define SRPW 10

// ---------------- K0: fused prep ------------------------------------------------------------
// blocks 0..39   : tA = text @ A^T  (bf16x3 split MFMA, hi/lo in-register)
// blocks 40..59  : TB = text @ Wh_bot + bh (same)
// blocks 60..315 : FbT[b][c][d][64n-pad] transpose (one block per (b,c); pad n>=50 zeroed)
// blocks 316..347: WhbT[j][k] transpose of Wh top half
// blocks 348..511: qpart tag zero-fill
__global__ __launch_bounds__(256) void k_prep(const float* __restrict__ F,
                                              const float* __restrict__ Wh,
                                              const float* __restrict__ text,
                                              const float* __restrict__ A,
                                              const float* __restrict__ bh,
                                              unsigned short* __restrict__ tAb,
                                              float* __restrict__ TB,
                                              unsigned short* __restrict__ WhbT,
                                              unsigned short* __restrict__ FbT,
                                              uint4* __restrict__ qzero) {
  __shared__ unsigned short Ahs[64 * LDH], Als[64 * LDH];
  __shared__ unsigned short Bhs[64 * LDH], Bls[64 * LDH];
  __shared__ float Tls[64 * 69];
  const int bid = blockIdx.x, tid = threadIdx.x;
  if (bid >= 60) {
    if (bid < 316) {
      // ---- FbT transpose: block -> (b,c) ----
      const int bb = (bid - 60) >> 3, cc = (bid - 60) & 7;
      const float* Fs = F + ((size_t)bb * NDIM + cc * SROWS) * DDIM;
      unsigned short* Ft = FbT + (size_t)(bb * SBLK + cc) * DDIM * 64;
      for (int d0 = 0; d0 < DDIM; d0 += 64) {
        for (int idx = tid; idx < 800; idx += 256) {
          int nr = idx >> 4, q = idx & 15;
          float4 v = *(const float4*)(Fs + (size_t)nr * DDIM + d0 + q * 4);
          Tls[nr * 69 + q * 4 + 0] = v.x;
          Tls[nr * 69 + q * 4 + 1] = v.y;
          Tls[nr * 69 + q * 4 + 2] = v.z;
          Tls[nr * 69 + q * 4 + 3] = v.w;
        }
        __syncthreads();
#pragma unroll
        for (int p = 0; p < 2; ++p) {
          int idx = p * 256 + tid;
          int dr = idx >> 3, oct = idx & 7;
          unsigned short us[8];
#pragma unroll
          for (int i = 0; i < 8; ++i) {
            int n = oct * 8 + i;
            us[i] = (n < SROWS) ? bf1(Tls[n * 69 + dr]) : (unsigned short)0;
          }
          *(uint4*)(Ft + (size_t)(d0 + dr) * 64 + oct * 8) = *(uint4*)us;
        }
        __syncthreads();
      }
      return;
    }
    if (bid < 348) {
      // ---- WhbT transpose: 32 tiles of [64 k][64 j] ----
      const int ti = bid - 316;
      const int k0 = (ti & 7) * 64, j0 = (ti >> 3) * 64;
      for (int idx = tid; idx < 1024; idx += 256) {
        int kr = idx >> 4, q = idx & 15;
        float4 v = *(const float4*)(Wh + (size_t)(k0 + kr) * HDIM + j0 + q * 4);
        Tls[kr * 69 + q * 4 + 0] = v.x;
        Tls[kr * 69 + q * 4 + 1] = v.y;
        Tls[kr * 69 + q * 4 + 2] = v.z;
        Tls[kr * 69 + q * 4 + 3] = v.w;
      }
      __syncthreads();
#pragma unroll
      for (int p = 0; p < 2; ++p) {
        int idx = p * 256 + tid;
        int jr = idx >> 3, oct = idx & 7;
        unsigned short us[8];
#pragma unroll
        for (int i = 0; i < 8; ++i) us[i] = bf1(Tls[(oct * 8 + i) * 69 + jr]);
        *(uint4*)(WhbT + (size_t)(j0 + jr) * DDIM + k0 + oct * 8) = *(uint4*)us;
      }
      return;
    }
    // ---- qpart zero ----
    const int NQ16 = 82176;  // (1310720 + 4096) / 16
    const int gid = (bid - 348) * 256 + tid;
    const int stride = 164 * 256;
    for (int i = gid; i < NQ16; i += stride) qzero[i] = make_uint4(0u, 0u, 0u, 0u);
    return;
  }
  // ---- GEMM planes (bf16x3 split MFMA) ----
  const int l = tid & 63, wv = tid >> 6;
  const int m = tid >> 2, kq = (tid & 3) * 8;
  f32x4 acc[4] = {};
  if (bid < 40) {
    const int d0 = (bid & 7) * 64, t0 = (bid >> 3) * 64;
    for (int k0 = 0; k0 < 512; k0 += 32) {
      {
        int t = t0 + m;
        float4 v0 = make_float4(0.f, 0.f, 0.f, 0.f), v1 = v0;
        if (t < TDIM) {
          v0 = *(const float4*)(text + (size_t)t * DDIM + k0 + kq);
          v1 = *(const float4*)(text + (size_t)t * DDIM + k0 + kq + 4);
        }
        *(uint4*)(&Ahs[m * LDH + kq]) =
            make_uint4(pack2(v0.x, v0.y), pack2(v0.z, v0.w), pack2(v1.x, v1.y), pack2(v1.z, v1.w));
        *(uint4*)(&Als[m * LDH + kq]) =
            make_uint4(pack2(bfres(v0.x), bfres(v0.y)), pack2(bfres(v0.z), bfres(v0.w)),
                       pack2(bfres(v1.x), bfres(v1.y)), pack2(bfres(v1.z), bfres(v1.w)));
        float4 w0 = *(const float4*)(A + (size_t)(d0 + m) * DDIM + k0 + kq);
        float4 w1 = *(const float4*)(A + (size_t)(d0 + m) * DDIM + k0 + kq + 4);
        *(uint4*)(&Bhs[m * LDH + kq]) =
            make_uint4(pack2(w0.x, w0.y), pack2(w0.z, w0.w), pack2(w1.x, w1.y), pack2(w1.z, w1.w));
        *(uint4*)(&Bls[m * LDH + kq]) =
            make_uint4(pack2(bfres(w0.x), bfres(w0.y)), pack2(bfres(w0.z), bfres(w0.w)),
                       pack2(bfres(w1.x), bfres(w1.y)), pack2(bfres(w1.z), bfres(w1.w)));
      }
      __syncthreads();
      bf16x8 ah = *(const bf16x8*)(&Ahs[(wv * 16 + (l & 15)) * LDH + (l >> 4) * 8]);
      bf16x8 al = *(const bf16x8*)(&Als[(wv * 16 + (l & 15)) * LDH + (l >> 4) * 8]);
#pragma unroll
      for (int c = 0; c < 4; ++c) {
        bf16x8 bh_ = *(const bf16x8*)(&Bhs[(c * 16 + (l & 15)) * LDH + (l >> 4) * 8]);
        bf16x8 bl_ = *(const bf16x8*)(&Bls[(c * 16 + (l & 15)) * LDH + (l >> 4) * 8]);
        acc[c] = __builtin_amdgcn_mfma_f32_16x16x32_bf16(ah, bh_, acc[c], 0, 0, 0);
        acc[c] = __builtin_amdgcn_mfma_f32_16x16x32_bf16(ah, bl_, acc[c], 0, 0, 0);
        acc[c] = __builtin_amdgcn_mfma_f32_16x16x32_bf16(al, bh_, acc[c], 0, 0, 0);
      }
      __syncthreads();
    }
#pragma unroll
    for (int c = 0; c < 4; ++c)
#pragma unroll
      for (int r = 0; r < 4; ++r) {
        int t = t0 + wv * 16 + ((l >> 4) << 2) + r;  // pad rows (>=315) are exact zeros
        int d = d0 + c * 16 + (l & 15);
        tAb[(size_t)t * DDIM + d] = bf1(acc[c][r]);
      }
  } else {
    const int idx = bid - 40;
    const int h0 = (idx & 3) * 64, t0 = (idx >> 2) * 64;
    const float* Wb = Wh + DDIM * HDIM;  // bottom half, [k][h]
    const int col = tid & 31, g = tid >> 5;
    for (int k0 = 0; k0 < 512; k0 += 32) {
      {
        int t = t0 + m;
        float4 v0 = make_float4(0.f, 0.f, 0.f, 0.f), v1 = v0;
        if (t < TDIM) {
          v0 = *(const float4*)(text + (size_t)t * DDIM + k0 + kq);
          v1 = *(const float4*)(text + (size_t)t * DDIM + k0 + kq + 4);
        }
        *(uint4*)(&Ahs[m * LDH + kq]) =
            make_uint4(pack2(v0.x, v0.y), pack2(v0.z, v0.w), pack2(v1.x, v1.y), pack2(v1.z, v1.w));
        *(uint4*)(&Als[m * LDH + kq]) =
            make_uint4(pack2(bfres(v0.x), bfres(v0.y)), pack2(bfres(v0.z), bfres(v0.w)),
                       pack2(bfres(v1.x), bfres(v1.y)), pack2(bfres(v1.z), bfres(v1.w)));
        float4 w0 = *(const float4*)(Wb + (size_t)(k0 + col) * HDIM + h0 + g * 8);
        float4 w1 = *(const float4*)(Wb + (size_t)(k0 + col) * HDIM + h0 + g * 8 + 4);
        float wr[8] = {w0.x, w0.y, w0.z, w0.w, w1.x, w1.y, w1.z, w1.w};
#pragma unroll
        for (int i = 0; i < 8; ++i) {
          Bhs[(g * 8 + i) * LDH + col] = bf1(wr[i]);
          Bls[(g * 8 + i) * LDH + col] = bf1(bfres(wr[i]));
        }
      }
      __syncthreads();
      bf16x8 ah = *(const bf16x8*)(&Ahs[(wv * 16 + (l & 15)) * LDH + (l >> 4) * 8]);
      bf16x8 al = *(const bf16x8*)(&Als[(wv * 16 + (l & 15)) * LDH + (l >> 4) * 8]);
#pragma unroll
      for (int c = 0; c < 4; ++c) {
        bf16x8 bh_ = *(const bf16x8*)(&Bhs[(c * 16 + (l & 15)) * LDH + (l >> 4) * 8]);
        bf16x8 bl_ = *(const bf16x8*)(&Bls[(c * 16 + (l & 15)) * LDH + (l >> 4) * 8]);
        acc[c] = __builtin_amdgcn_mfma_f32_16x16x32_bf16(ah, bh_, acc[c], 0, 0, 0);
        acc[c] = __builtin_amdgcn_mfma_f32_16x16x32_bf16(ah, bl_, acc[c], 0, 0, 0);
        acc[c] = __builtin_amdgcn_mfma_f32_16x16x32_bf16(al, bh_, acc[c], 0, 0, 0);
      }
      __syncthreads();
    }
#pragma unroll
    for (int c = 0; c < 4; ++c)
#pragma unroll
      for (int r = 0; r < 4; ++r) {
        int t = t0 + wv * 16 + ((l >> 4) << 2) + r;
        int h = h0 + c * 16 + (l & 15);
        TB[(size_t)t * HDIM + h] = acc[c][r] + bh[h];
      }
  }
}

// ---------------- K3: fused s-GEMM + instnorm + sinkhorn (s1T output) -----------------------
// F staged fp32 -> bf16 in-register (bit-identical to the old pre-packed Fb path).
__global__ __launch_bounds__(320, 1) void k_sinkhorn(const float* __restrict__ F,
                                                     const unsigned short* __restrict__ tAb,
                                                     const float* __restrict__ gptr,
                                                     const float* __restrict__ bptr,
                                                     unsigned short* __restrict__ s1T,
                                                     ull* __restrict__ qpart) {
  __shared__ unsigned short Fch[64 * LDH];    // F rows chunk   [64][32]
  __shared__ unsigned short tACh[320 * LDH];  // tA rows chunk  [320][32]
  __shared__ float Sls[SROWS * 320];          // S-tile fp32 (reused as bf16 [320][72] later)
  __shared__ float qpl[5][320];               // per-wave own col partials
  __shared__ float qg[5][320];                // per-wave gathered cc-slice sums
  __shared__ float sred[16];
  const int b = blockIdx.x, c = blockIdx.y;
  const int tid = threadIdx.x, wv = tid >> 6, l = tid & 63;
  const float* Fs = F + ((size_t)b * NDIM + (size_t)c * SROWS) * DDIM;
  const float TOL = 1e-3f;
  const float TN_RATIO = 315.0f / 400.0f;

  // ---- phase 1: S-tile MFMA ----
  f32x4 acc[16] = {};  // [tt][nt]
  {
    const int m = tid >> 2, kq = (tid & 3) * 8;
    for (int k0 = 0; k0 < 512; k0 += 32) {
      if (m < 64) {
        uint4 fv = make_uint4(0, 0, 0, 0);
        if (m < SROWS) {
          float4 v0 = *(const float4*)(Fs + (size_t)m * DDIM + k0 + kq);
          float4 v1 = *(const float4*)(Fs + (size_t)m * DDIM + k0 + kq + 4);
          fv = make_uint4(pack2(v0.x, v0.y), pack2(v0.z, v0.w),
                          pack2(v1.x, v1.y), pack2(v1.z, v1.w));
        }
        *(uint4*)(&Fch[m * LDH + kq]) = fv;
      }
#pragma unroll
      for (int p = 0; p < 4; ++p) {
        int row = p * 80 + m;
        *(uint4*)(&tACh[row * LDH + kq]) = *(const uint4*)(tAb + (size_t)row * DDIM + k0 + kq);
      }
      __syncthreads();
      bf16x8 af[4];
#pragma unroll
      for (int nt = 0; nt < 4; ++nt)
        af[nt] = *(const bf16x8*)(&Fch[(nt * 16 + (l & 15)) * LDH + (l >> 4) * 8]);
#pragma unroll
      for (int tt = 0; tt < 4; ++tt) {
        bf16x8 bf_ = *(const bf16x8*)(&tACh[((wv * 4 + tt) * 16 + (l & 15)) * LDH + (l >> 4) * 8]);
#pragma unroll
        for (int nt = 0; nt < 4; ++nt)
          acc[tt * 4 + nt] = __builtin_amdgcn_mfma_f32_16x16x32_bf16(af[nt], bf_, acc[tt * 4 + nt], 0, 0, 0);
      }
      __syncthreads();
    }
  }
  // ---- write S-tile to LDS + local stats partial ----
  float ls = 0.f, lq = 0.f;
#pragma unroll
  for (int tt = 0; tt < 4; ++tt) {
    int t = (wv * 4 + tt) * 16 + (l & 15);
    bool tv = (t < TDIM);
#pragma unroll
    for (int nt = 0; nt < 4; ++nt)
#pragma unroll
      for (int r = 0; r < 4; ++r) {
        int n = nt * 16 + ((l >> 4) << 2) + r;
        if (n < SROWS && tv) {
          float v = acc[tt * 4 + nt][r];
          Sls[n * 320 + t] = v;
          ls += v;
          lq = fmaf(v, v, lq);
        }
      }
  }
#pragma unroll
  for (int mm = 1; mm <= 32; mm <<= 1) {
    ls += __shfl_xor(ls, mm, 64);
    lq += __shfl_xor(lq, mm, 64);
  }
  if (l == 0) { sred[wv] = ls; sred[8 + wv] = lq; }
  __syncthreads();
  // ---- stats exchange ----
  {
    ull* satoms = qpart + QSTATS;
    if (tid == 0) {
      float Ssum = sred[0] + sred[1] + sred[2] + sred[3] + sred[4];
      float Sq = sred[8] + sred[9] + sred[10] + sred[11] + sred[12];
      ull* mine = satoms + ((size_t)b * SBLK + c) * 2;
      __hip_atomic_store(&mine[0], (1ull << 32) | (ull)__float_as_uint(Ssum),
                         __ATOMIC_RELAXED, __HIP_MEMORY_SCOPE_AGENT);
      __hip_atomic_store(&mine[1], (1ull << 32) | (ull)__float_as_uint(Sq),
                         __ATOMIC_RELAXED, __HIP_MEMORY_SCOPE_AGENT);
    }
    if (wv == 0) {
      ull g = (1ull << 32);
      const ull* base = satoms + (size_t)b * SBLK * 2;
      if (l < 16) g = __hip_atomic_load(&base[l], __ATOMIC_RELAXED, __HIP_MEMORY_SCOPE_AGENT);
      int guard = 0;
      for (;;) {
        if (__ballot((unsigned)(g >> 32) >= 1u) == ~0ull) break;
        if (++guard > (1 << 20)) break;  // deadlock escape (should never trigger)
        if (l < 16 && (unsigned)(g >> 32) < 1u)
          g = __hip_atomic_load(&base[l], __ATOMIC_RELAXED, __HIP_MEMORY_SCOPE_AGENT);
      }
      if (l < 16) sred[l] = __uint_as_float((unsigned)g);
    }
  }
  __syncthreads();
  const float NT = 400.0f * 315.0f;
  const float Ssum_all = ((sred[0] + sred[2]) + (sred[4] + sred[6])) +
                         ((sred[8] + sred[10]) + (sred[12] + sred[14]));
  const float Sq_all = ((sred[1] + sred[3]) + (sred[5] + sred[7])) +
                       ((sred[9] + sred[11]) + (sred[13] + sred[15]));
  const float mean = Ssum_all / NT;
  const float var = Sq_all / NT - mean * mean;
  const float inv = rsqrtf(var + 1e-5f);
  const float alpha = gptr[0] * inv;
  const float L2E = 1.4426950408889634f;
  const float a2 = alpha * L2E;
  const float d2 = (bptr[0] - mean * alpha) * L2E;

  // ---- E = exp(instnorm(S)) from fp32 LDS ----
  float E0[SRPW], E1[SRPW], E2[SRPW], E3[SRPW], E4[SRPW];
#pragma unroll
  for (int j = 0; j < SRPW; ++j) {
    const float* row = Sls + (wv * SRPW + j) * 320;
    E0[j] = __builtin_amdgcn_exp2f(fmaf(row[l], a2, d2));
    E1[j] = __builtin_amdgcn_exp2f(fmaf(row[64 + l], a2, d2));
    E2[j] = __builtin_amdgcn_exp2f(fmaf(row[128 + l], a2, d2));
    E3[j] = __builtin_amdgcn_exp2f(fmaf(row[192 + l], a2, d2));
    E4[j] = (l < 59) ? __builtin_amdgcn_exp2f(fmaf(row[256 + l], a2, d2)) : 0.0f;
  }
  float w0 = 1.0f, w1 = 1.0f, w2 = 1.0f, w3 = 1.0f, w4 = (l < 59) ? 1.0f : 0.0f;
  float aj[SRPW];
#pragma unroll
  for (int j = 0; j < SRPW; ++j) aj[j] = 0.0f;

  bool fin = false;
  for (int it = 0; it < NITER; ++it) {
    float p[SRPW];
#pragma unroll
    for (int j = 0; j < SRPW; ++j) {
      float t = E4[j] * w4;
      t = fmaf(E3[j], w3, t);
      t = fmaf(E2[j], w2, t);
      t = fmaf(E1[j], w1, t);
      p[j] = fmaf(E0[j], w0, t);
    }
#pragma unroll
    for (int j = 0; j < SRPW; ++j) p[j] = dppadd<0x111, 0xf>(p[j]);
#pragma unroll
    for (int j = 0; j < SRPW; ++j) p[j] = dppadd<0x112, 0xf>(p[j]);
#pragma unroll
    for (int j = 0; j < SRPW; ++j) p[j] = dppadd<0x114, 0xf>(p[j]);
#pragma unroll
    for (int j = 0; j < SRPW; ++j) p[j] = dppadd<0x118, 0xf>(p[j]);
#pragma unroll
    for (int j = 0; j < SRPW; ++j) p[j] = dppadd<0x142, 0xa>(p[j]);
#pragma unroll
    for (int j = 0; j < SRPW; ++j) p[j] = dppadd<0x143, 0xc>(p[j]);
#pragma unroll
    for (int j = 0; j < SRPW; ++j) {
      float r = __builtin_amdgcn_rcpf(p[j]);
      aj[j] = __int_as_float(__builtin_amdgcn_readlane(__float_as_int(r), 63));
    }
    float q0 = 0.f, q1 = 0.f, q2 = 0.f, q3 = 0.f, q4 = 0.f;
#pragma unroll
    for (int j = 0; j < SRPW; ++j) {
      q0 = fmaf(E0[j], aj[j], q0);
      q1 = fmaf(E1[j], aj[j], q1);
      q2 = fmaf(E2[j], aj[j], q2);
      q3 = fmaf(E3[j], aj[j], q3);
      q4 = fmaf(E4[j], aj[j], q4);
    }
    qpl[wv][l] = q0;
    qpl[wv][64 + l] = q1;
    qpl[wv][128 + l] = q2;
    qpl[wv][192 + l] = q3;
    qpl[wv][256 + l] = q4;
    __syncthreads();
    const int par = it & 1;
    const unsigned tgt = (unsigned)(it + 1);
    ull* bufpar = qpart + ((size_t)par * BDIM + b) * (SBLK * 320);
    if (wv == 0) {
      ull* myp = bufpar + c * 320;
#pragma unroll
      for (int k = 0; k < 5; ++k) {
        int t = k * 64 + l;
        float sm = qpl[0][t] + qpl[1][t] + qpl[2][t] + qpl[3][t] + qpl[4][t];
        __hip_atomic_store(&myp[t], ((ull)tgt << 32) | (ull)__float_as_uint(sm),
                           __ATOMIC_RELAXED, __HIP_MEMORY_SCOPE_AGENT);
      }
    }
    {
      const int ncc = (wv < 3) ? 2 : 1;
      ull got[2][5];
      const int ccs[2] = {wv, wv + 5};
#pragma unroll
      for (int e = 0; e < 2; ++e)
        if (e < ncc && ccs[e] != c) {
#pragma unroll
          for (int k = 0; k < 5; ++k)
            got[e][k] = __hip_atomic_load(&bufpar[ccs[e] * 320 + k * 64 + l],
                                          __ATOMIC_RELAXED, __HIP_MEMORY_SCOPE_AGENT);
        }
      int guard = 0;
      for (;;) {
        bool ok = true;
#pragma unroll
        for (int e = 0; e < 2; ++e)
          if (e < ncc && ccs[e] != c) {
#pragma unroll
            for (int k = 0; k < 5; ++k)
              if ((unsigned)(got[e][k] >> 32) != tgt) {
                got[e][k] = __hip_atomic_load(&bufpar[ccs[e] * 320 + k * 64 + l],
                                              __ATOMIC_RELAXED, __HIP_MEMORY_SCOPE_AGENT);
                ok = false;
              }
          }
        if (ok) break;
        if (++guard > (1 << 20)) break;  // deadlock escape (should never trigger)
      }
      float part[5] = {0.f, 0.f, 0.f, 0.f, 0.f};
#pragma unroll
      for (int e = 0; e < 2; ++e)
        if (e < ncc) {
#pragma unroll
          for (int k = 0; k < 5; ++k) {
            int t = k * 64 + l;
            float v = (ccs[e] == c)
                          ? (qpl[0][t] + qpl[1][t] + qpl[2][t] + qpl[3][t] + qpl[4][t])
                          : __uint_as_float((unsigned)got[e][k]);
            part[k] += v;
          }
        }
#pragma unroll
      for (int k = 0; k < 5; ++k) qg[wv][k * 64 + l] = part[k];
    }
    __syncthreads();
    const float Q0 = qg[0][l] + qg[1][l] + qg[2][l] + qg[3][l] + qg[4][l];
    const float Q1 = qg[0][64 + l] + qg[1][64 + l] + qg[2][64 + l] + qg[3][64 + l] + qg[4][64 + l];
    const float Q2 =
        qg[0][128 + l] + qg[1][128 + l] + qg[2][128 + l] + qg[3][128 + l] + qg[4][128 + l];
    const float Q3 =
        qg[0][192 + l] + qg[1][192 + l] + qg[2][192 + l] + qg[3][192 + l] + qg[4][192 + l];
    const float Q4 =
        qg[0][256 + l] + qg[1][256 + l] + qg[2][256 + l] + qg[3][256 + l] + qg[4][256 + l];
    float r = fabsf(fmaf(Q0 * w0, TN_RATIO, -1.0f));
    r = fmaxf(r, fabsf(fmaf(Q1 * w1, TN_RATIO, -1.0f)));
    r = fmaxf(r, fabsf(fmaf(Q2 * w2, TN_RATIO, -1.0f)));
    r = fmaxf(r, fabsf(fmaf(Q3 * w3, TN_RATIO, -1.0f)));
    if (l < 59) r = fmaxf(r, fabsf(fmaf(Q4 * w4, TN_RATIO, -1.0f)));
    w0 = __builtin_amdgcn_rcpf(Q0);
    w1 = __builtin_amdgcn_rcpf(Q1);
    w2 = __builtin_amdgcn_rcpf(Q2);
    w3 = __builtin_amdgcn_rcpf(Q3);
    if (l < 59) w4 = __builtin_amdgcn_rcpf(Q4);
    if (fin) break;
    r = dppmax<0x111, 0xf>(r);
    r = dppmax<0x112, 0xf>(r);
    r = dppmax<0x114, 0xf>(r);
    r = dppmax<0x118, 0xf>(r);
    r = dppmax<0x142, 0xa>(r);
    r = dppmax<0x143, 0xc>(r);
    const float resid = __int_as_float(__builtin_amdgcn_readlane(__float_as_int(r), 63));
    fin = (resid < TOL) || (it == NITER - 2);
  }

  // ---- epilogue: s1 -> LDS bf16 transpose tile [320 t][72 pad n] -> s1T coalesced ----
  {
    unsigned short* SlsT = (unsigned short*)Sls;
#pragma unroll
    for (int j = 0; j < SRPW; ++j) {
      const int n = wv * SRPW + j;
      const float a = aj[j];
      SlsT[(size_t)l * 72 + n] = bf1(a * E0[j] * w0);
      SlsT[(size_t)(64 + l) * 72 + n] = bf1(a * E1[j] * w1);
      SlsT[(size_t)(128 + l) * 72 + n] = bf1(a * E2[j] * w2);
      SlsT[(size_t)(192 + l) * 72 + n] = bf1(a * E3[j] * w3);
      SlsT[(size_t)(256 + l) * 72 + n] = (l < 59) ? bf1(a * E4[j] * w4) : (unsigned short)0;
    }
    for (int i = tid; i < 320 * 14; i += 320) {
      int t = i / 14, n = 50 + (i % 14);
      SlsT[(size_t)t * 72 + n] = 0;
    }
    __syncthreads();
    unsigned short* S1c = s1T + (size_t)(b * SBLK + c) * 320 * 64;
    for (int i = tid; i < 320 * 8; i += 320) {
      int row = i >> 3, oct = i & 7;
      *(uint4*)(S1c + (size_t)row * 64 + oct * 8) =
          *(const uint4*)(SlsT + (size_t)row * 72 + oct * 8);
    }
  }
}

// ---------------- K4: fused f1 + h + pred ---------------------------------------------------
// Grid (32 b, 5 tt). Phase 1: f1_tile[64 t][512 d] = sum_c s1T[c][t][:].FbT[c][d][:]
// (K=512 padded n; pads are exact zeros). All staging natural-row uint4. f1 tile held in
// LDS bf16 (identical rounding to the old f1b buffer). Phase 2: h=relu(f1@WhbT^T + TB),
// pred = h@Wo + bo, direct store. Batch-major grid -> per-batch set XCD/L2-resident.
__global__ __launch_bounds__(256) void k_out(const unsigned short* __restrict__ s1T,
                                             const unsigned short* __restrict__ FbT,
                                             const unsigned short* __restrict__ WhbT,
                                             const float* __restrict__ TB,
                                             const float* __restrict__ Wo,
                                             const float* __restrict__ bo,
                                             float* __restrict__ out) {
  __shared__ unsigned short Abf[64 * LDH];   // 5 KB
  __shared__ unsigned short Bbf[512 * LDH];  // 40 KB (reused in phase 2 for WhbT)
  __shared__ unsigned short f1L[64 * 520];   // 66.6 KB
  __shared__ float Wos[256];
  __shared__ float predp[4][64];
  const int b = blockIdx.x, t0 = blockIdx.y * 64;
  const int tid = threadIdx.x, l = tid & 63, wv = tid >> 6;
  Wos[tid] = Wo[tid];
  const unsigned short* S1b = s1T + (size_t)b * SBLK * 320 * 64;
  const unsigned short* Fbt = FbT + (size_t)b * SBLK * DDIM * 64;
  const int m = tid >> 2, kq = (tid & 3) * 8;
  // ---- phase 1 ----
  f32x4 acc[32] = {};  // [tt][dt] : wave owns 64 t x 128 d
  for (int ch = 0; ch < 16; ++ch) {
    const int c = ch >> 1, h = ch & 1;
    *(uint4*)(&Abf[m * LDH + kq]) =
        *(const uint4*)(S1b + ((size_t)c * 320 + t0 + m) * 64 + h * 32 + kq);
#pragma unroll
    for (int p = 0; p < 8; ++p) {
      int idx = p * 256 + tid;
      int d = idx >> 2, q = idx & 3;
      *(uint4*)(&Bbf[d * LDH + q * 8]) =
          *(const uint4*)(Fbt + ((size_t)c * DDIM + d) * 64 + h * 32 + q * 8);
    }
    __syncthreads();
    bf16x8 af[4];
#pragma unroll
    for (int tt = 0; tt < 4; ++tt)
      af[tt] = *(const bf16x8*)(&Abf[(tt * 16 + (l & 15)) * LDH + (l >> 4) * 8]);
#pragma unroll
    for (int dt = 0; dt < 8; ++dt) {
      bf16x8 bf_ = *(const bf16x8*)(&Bbf[(wv * 128 + dt * 16 + (l & 15)) * LDH + (l >> 4) * 8]);
#pragma unroll
      for (int tt = 0; tt < 4; ++tt)
        acc[tt * 8 + dt] =
            __builtin_amdgcn_mfma_f32_16x16x32_bf16(af[tt], bf_, acc[tt * 8 + dt], 0, 0, 0);
    }
    __syncthreads();
  }
  // ---- f1 tile -> LDS bf16 ----
#pragma unroll
  for (int tt = 0; tt < 4; ++tt)
#pragma unroll
    for (int dt = 0; dt < 8; ++dt)
#pragma unroll
      for (int r = 0; r < 4; ++r) {
        int t_loc = tt * 16 + ((l >> 4) << 2) + r;
        int d = wv * 128 + dt * 16 + (l & 15);
        f1L[t_loc * 520 + d] = bf1(acc[tt * 8 + dt][r]);
      }
  __syncthreads();
  // ---- phase 2 ----
  f32x4 acc2[16] = {};  // [rt][jt] : wave owns 64 r x 64 j
  for (int k0 = 0; k0 < 512; k0 += 32) {
#pragma unroll
    for (int p = 0; p < 4; ++p) {
      int idx = p * 256 + tid;
      int j = idx >> 2, q = idx & 3;
      *(uint4*)(&Bbf[j * LDH + q * 8]) = *(const uint4*)(WhbT + (size_t)j * DDIM + k0 + q * 8);
    }
    __syncthreads();
    bf16x8 af2[4];
#pragma unroll
    for (int rt = 0; rt < 4; ++rt)
      af2[rt] = *(const bf16x8*)(&f1L[(rt * 16 + (l & 15)) * 520 + (l >> 4) * 8 + k0]);
#pragma unroll
    for (int jt = 0; jt < 4; ++jt) {
      bf16x8 bf_ = *(const bf16x8*)(&Bbf[(wv * 64 + jt * 16 + (l & 15)) * LDH + (l >> 4) * 8]);
#pragma unroll
      for (int rt = 0; rt < 4; ++rt)
        acc2[rt * 4 + jt] =
            __builtin_amdgcn_mfma_f32_16x16x32_bf16(af2[rt], bf_, acc2[rt * 4 + jt], 0, 0, 0);
    }
    __syncthreads();
  }
  // ---- epilogue: relu(h + TB) . Wo, reduce over j ----
  float part[16];
#pragma unroll
  for (int i = 0; i < 16; ++i) part[i] = 0.f;
#pragma unroll
  for (int jt = 0; jt < 4; ++jt) {
    int j = wv * 64 + jt * 16 + (l & 15);
    float woc = Wos[j];
#pragma unroll
    for (int rt = 0; rt < 4; ++rt)
#pragma unroll
      for (int r = 0; r < 4; ++r) {
        int t = t0 + rt * 16 + ((l >> 4) << 2) + r;
        float v = acc2[rt * 4 + jt][r] + TB[(size_t)t * HDIM + j];
        part[rt * 4 + r] = fmaf(fmaxf(v, 0.f), woc, part[rt * 4 + r]);
      }
  }
#pragma unroll
  for (int i = 0; i < 16; ++i) part[i] = dppadd<0x111, 0xf>(part[i]);
#pragma unroll
  for (int i = 0; i < 16; ++i) part[i] = dppadd<0x112, 0xf>(part[i]);
#pragma unroll
  for (int i = 0; i < 16; ++i) part[i] = dppadd<0x114, 0xf>(part[i]);
#pragma unroll
  for (int i = 0; i < 16; ++i) part[i] = dppadd<0x118, 0xf>(part[i]);
  if ((l & 15) == 15) {
#pragma unroll
    for (int rt = 0; rt < 4; ++rt)
#pragma unroll
      for (int r = 0; r < 4; ++r)
        predp[wv][rt * 16 + ((l >> 4) << 2) + r] = part[rt * 4 + r];
  }
  __syncthreads();
  if (tid < 64) {
    int t = t0 + tid;
    if (t < TDIM)
      out[(size_t)b * TDIM + t] =
          predp[0][tid] + predp[1][tid] + predp[2][tid] + predp[3][tid] + bo[0];
  }
}

// ---------------- launch ----------------
extern "C" void kernel_launch(void* const* d_in, const int* in_sizes, int n_in,
                              void* d_out, int out_size, void* d_ws, size_t ws_size,
                              hipStream_t stream) {
  const float* F     = (const float*)d_in[0];
  const float* text  = (const float*)d_in[1];
  const float* A     = (const float*)d_in[2];
  const float* gamma = (const float*)d_in[3];
  const float* beta  = (const float*)d_in[4];
  const float* Wh    = (const float*)d_in[5];
  const float* bh    = (const float*)d_in[6];
  const float* Wo    = (const float*)d_in[7];
  const float* bo    = (const float*)d_in[8];
  float* out = (float*)d_out;
  char* ws = (char*)d_ws;
  unsigned short* tAb  = (unsigned short*)(ws + OFS_TAB);
  float* TB     = (float*)(ws + OFS_TB);
  unsigned short* WhbT = (unsigned short*)(ws + OFS_WHT);
  ull* qpart    = (ull*)(ws + OFS_QPART);
  unsigned short* s1T  = (unsigned short*)(ws + OFS_S1T);
  unsigned short* FbT  = (unsigned short*)(ws + OFS_FBT);

  k_prep<<<512, 256, 0, stream>>>(F, Wh, text, A, bh, tAb, TB, WhbT, FbT, (uint4*)qpart);
  k_sinkhorn<<<dim3(BDIM, SBLK), 320, 0, stream>>>(F, tAb, gamma, beta, s1T, qpart);
  k_out<<<dim3(BDIM, 5), 256, 0, stream>>>(s1T, FbT, WhbT, TB, Wo, bo, out);
}